// Round 12
// baseline (2706.495 us; speedup 1.0000x reference)
//
#include <hip/hip_runtime.h>
#include <hip/hip_bf16.h>

#define B_ 32
#define T_ 2000
#define S_ 400
#define C0_ 80
#define H_ 256

static constexpr float NEGV = -1e9f;
static constexpr int NMU  = B_ * T_ * S_;       // 25,600,000
static constexpr int NPI  = 2 * NMU;            // 51,200,000

typedef _Float16 f16x8 __attribute__((ext_vector_type(8)));
typedef float    f32x4 __attribute__((ext_vector_type(4)));

// ---------------- weight repack: wcat[co][k*CPAD+ci] = w[k][ci][co] ------
__global__ __launch_bounds__(256)
void wprep(const float* __restrict__ w, _Float16* __restrict__ wcat,
           int CIN, int CPAD)
{
  const int tot = 256 * 5 * CPAD;
  int idx = blockIdx.x * 256 + threadIdx.x;
  if (idx >= tot) return;
  int co  = idx / (5 * CPAD);
  int rem = idx - co * (5 * CPAD);
  int k   = rem / CPAD;
  int ci  = rem - k * CPAD;
  float v = (ci < CIN) ? w[((size_t)k * CIN + ci) * H_ + co] : 0.f;
  wcat[idx] = (_Float16)v;
}

// ---------------- conv1d (K=5, SAME) + bias + tanh via f16 MFMA ----------
template<int CIN, int CPAD, bool INF32, bool OUTF32>
__global__ __launch_bounds__(256)
void conv_mfma(const void* __restrict__ xin, const _Float16* __restrict__ wcat,
               const float* __restrict__ bias, void* __restrict__ yout)
{
  constexpr int KK  = 5 * CPAD;      // 480 / 1280
  constexpr int NS  = KK / 32;       // 15 / 40
  constexpr int STR = CPAD + 8;      // LDS row stride
  __shared__ _Float16 xs[68 * STR];
  const int b   = blockIdx.y;
  const int t0  = blockIdx.x * 64;
  const int tid = threadIdx.x;
  const int w   = tid >> 6;
  const int l   = tid & 63;

  if constexpr (INF32) {
    const float* xb = (const float*)xin + (size_t)b * T_ * CIN;
    constexpr int NG = CPAD / 4;
    for (int idx = tid; idx < 68 * NG; idx += 256) {
      int j = idx / NG, g = idx - j * NG;
      int t = t0 - 2 + j;
      int c = g * 4;
      float4 v = make_float4(0.f, 0.f, 0.f, 0.f);
      if (t >= 0 && t < T_ && c < CIN) v = *(const float4*)&xb[(size_t)t * CIN + c];
      _Float16* d = &xs[j * STR + c];
      d[0] = (_Float16)v.x; d[1] = (_Float16)v.y;
      d[2] = (_Float16)v.z; d[3] = (_Float16)v.w;
    }
  } else {
    const _Float16* xb = (const _Float16*)xin + (size_t)b * T_ * CIN;
    constexpr int NG = CPAD / 8;
    for (int idx = tid; idx < 68 * NG; idx += 256) {
      int j = idx / NG, g = idx - j * NG;
      int t = t0 - 2 + j;
      f16x8 v = {(_Float16)0,(_Float16)0,(_Float16)0,(_Float16)0,
                 (_Float16)0,(_Float16)0,(_Float16)0,(_Float16)0};
      if (t >= 0 && t < T_) v = *(const f16x8*)&xb[(size_t)t * CIN + g * 8];
      *(f16x8*)&xs[j * STR + g * 8] = v;
    }
  }
  __syncthreads();

  const int lr = l & 15;
  const int lk = (l >> 4) * 8;

  f32x4 acc[4][4];
  const f32x4 zz = {0.f, 0.f, 0.f, 0.f};
#pragma unroll
  for (int i = 0; i < 4; i++)
#pragma unroll
    for (int j = 0; j < 4; j++) acc[i][j] = zz;

  const _Float16* wbase = wcat + (size_t)(w * 64 + lr) * KK + lk;

  for (int kk = 0; kk < NS; kk++) {
    const int p  = kk * 32;
    const int k  = p / CPAD;
    const int ci = p - k * CPAD;
    f16x8 a0 = *(const f16x8*)&xs[( 0 + lr + k) * STR + ci + lk];
    f16x8 a1 = *(const f16x8*)&xs[(16 + lr + k) * STR + ci + lk];
    f16x8 a2 = *(const f16x8*)&xs[(32 + lr + k) * STR + ci + lk];
    f16x8 a3 = *(const f16x8*)&xs[(48 + lr + k) * STR + ci + lk];
    f16x8 w0 = *(const f16x8*)&wbase[(size_t)( 0) * KK + p];
    f16x8 w1 = *(const f16x8*)&wbase[(size_t)(16) * KK + p];
    f16x8 w2 = *(const f16x8*)&wbase[(size_t)(32) * KK + p];
    f16x8 w3 = *(const f16x8*)&wbase[(size_t)(48) * KK + p];
    acc[0][0] = __builtin_amdgcn_mfma_f32_16x16x32_f16(a0, w0, acc[0][0], 0, 0, 0);
    acc[0][1] = __builtin_amdgcn_mfma_f32_16x16x32_f16(a0, w1, acc[0][1], 0, 0, 0);
    acc[0][2] = __builtin_amdgcn_mfma_f32_16x16x32_f16(a0, w2, acc[0][2], 0, 0, 0);
    acc[0][3] = __builtin_amdgcn_mfma_f32_16x16x32_f16(a0, w3, acc[0][3], 0, 0, 0);
    acc[1][0] = __builtin_amdgcn_mfma_f32_16x16x32_f16(a1, w0, acc[1][0], 0, 0, 0);
    acc[1][1] = __builtin_amdgcn_mfma_f32_16x16x32_f16(a1, w1, acc[1][1], 0, 0, 0);
    acc[1][2] = __builtin_amdgcn_mfma_f32_16x16x32_f16(a1, w2, acc[1][2], 0, 0, 0);
    acc[1][3] = __builtin_amdgcn_mfma_f32_16x16x32_f16(a1, w3, acc[1][3], 0, 0, 0);
    acc[2][0] = __builtin_amdgcn_mfma_f32_16x16x32_f16(a2, w0, acc[2][0], 0, 0, 0);
    acc[2][1] = __builtin_amdgcn_mfma_f32_16x16x32_f16(a2, w1, acc[2][1], 0, 0, 0);
    acc[2][2] = __builtin_amdgcn_mfma_f32_16x16x32_f16(a2, w2, acc[2][2], 0, 0, 0);
    acc[2][3] = __builtin_amdgcn_mfma_f32_16x16x32_f16(a2, w3, acc[2][3], 0, 0, 0);
    acc[3][0] = __builtin_amdgcn_mfma_f32_16x16x32_f16(a3, w0, acc[3][0], 0, 0, 0);
    acc[3][1] = __builtin_amdgcn_mfma_f32_16x16x32_f16(a3, w1, acc[3][1], 0, 0, 0);
    acc[3][2] = __builtin_amdgcn_mfma_f32_16x16x32_f16(a3, w2, acc[3][2], 0, 0, 0);
    acc[3][3] = __builtin_amdgcn_mfma_f32_16x16x32_f16(a3, w3, acc[3][3], 0, 0, 0);
  }

#pragma unroll
  for (int ct = 0; ct < 4; ct++) {
    const int co = w * 64 + ct * 16 + lr;
    const float bv = bias[co];
#pragma unroll
    for (int tt = 0; tt < 4; tt++) {
#pragma unroll
      for (int r = 0; r < 4; r++) {
        const int t = t0 + tt * 16 + (l >> 4) * 4 + r;
        if (t < T_) {
          float v = tanhf(acc[tt][ct][r] + bv);
          if constexpr (OUTF32)
            ((float*)yout)[((size_t)b * T_ + t) * H_ + co] = v;
          else
            ((_Float16*)yout)[((size_t)b * T_ + t) * H_ + co] = (_Float16)v;
        }
      }
    }
  }
}

// ---------------- W[b,t,s] = sum_h Wspec[b,t,h] * src_enc[b,s,h] --------
__global__ __launch_bounds__(256)
void einsum_ts(const float* __restrict__ A, const float* __restrict__ E,
               float* __restrict__ Wg)
{
  constexpr int GT = 128, GS = 64, KC = 16;
  __shared__ float As[KC][GT + 4];
  __shared__ float Bs[KC][GS + 4];
  const int b   = blockIdx.z;
  const int t0  = blockIdx.x * GT;
  const int s0  = blockIdx.y * GS;
  const int tid = threadIdx.x;
  const int tx  = tid & 15;
  const int ty  = tid >> 4;
  float4 acc[8];
#pragma unroll
  for (int i = 0; i < 8; i++) acc[i] = make_float4(0.f, 0.f, 0.f, 0.f);
  const float* Ab = A + (size_t)b * T_ * H_;
  const float* Eb = E + (size_t)b * S_ * H_;
  for (int kc = 0; kc < H_; kc += KC) {
#pragma unroll
    for (int r = 0; r < 2; r++) {
      int f4  = tid + 256 * r;
      int row = f4 >> 2;
      int c4  = f4 & 3;
      int t   = t0 + row;
      float4 v = make_float4(0, 0, 0, 0);
      if (t < T_) v = *(const float4*)&Ab[(size_t)t * H_ + kc + c4 * 4];
      As[c4*4+0][row] = v.x; As[c4*4+1][row] = v.y;
      As[c4*4+2][row] = v.z; As[c4*4+3][row] = v.w;
    }
    {
      int row = tid >> 2;
      int c4  = tid & 3;
      int s   = s0 + row;
      float4 v = make_float4(0, 0, 0, 0);
      if (s < S_) v = *(const float4*)&Eb[(size_t)s * H_ + kc + c4 * 4];
      Bs[c4*4+0][row] = v.x; Bs[c4*4+1][row] = v.y;
      Bs[c4*4+2][row] = v.z; Bs[c4*4+3][row] = v.w;
    }
    __syncthreads();
#pragma unroll
    for (int kk = 0; kk < KC; kk++) {
      float4 a0 = *(const float4*)&As[kk][ty * 8];
      float4 a1 = *(const float4*)&As[kk][ty * 8 + 4];
      float4 bb = *(const float4*)&Bs[kk][tx * 4];
      float av[8] = {a0.x, a0.y, a0.z, a0.w, a1.x, a1.y, a1.z, a1.w};
#pragma unroll
      for (int i = 0; i < 8; i++) {
        acc[i].x = fmaf(av[i], bb.x, acc[i].x);
        acc[i].y = fmaf(av[i], bb.y, acc[i].y);
        acc[i].z = fmaf(av[i], bb.z, acc[i].z);
        acc[i].w = fmaf(av[i], bb.w, acc[i].w);
      }
    }
    __syncthreads();
  }
  float* Wb = Wg + (size_t)b * T_ * S_;
  const int s = s0 + tx * 4;
#pragma unroll
  for (int i = 0; i < 8; i++) {
    int t = t0 + ty * 8 + i;
    if (t < T_ && s < S_) *(float4*)&Wb[(size_t)t * S_ + s] = acc[i];
  }
}

// ---------------- per-(b,s) column softmax stats over T ------------------
__global__ __launch_bounds__(256)
void softmax_stats(const float* __restrict__ Wg, float* __restrict__ statsOut)
{
  const int b  = blockIdx.y;
  const int tx = threadIdx.x & 63;
  const int ty = threadIdx.x >> 6;            // 0..3
  const int s  = blockIdx.x * 64 + tx;
  const bool act = (s < S_);
  float m = -1e30f, l = 0.f;
  if (act) {
    const float* col = Wg + (size_t)b * T_ * S_ + s;
#pragma unroll 4
    for (int t = ty; t < T_; t += 4) {
      float v  = col[(size_t)t * S_];
      float nm = fmaxf(m, v);
      l = l * __expf(m - nm) + __expf(v - nm);
      m = nm;
    }
  }
  __shared__ float rm[4][64], rl[4][64];
  rm[ty][tx] = m; rl[ty][tx] = l;
  __syncthreads();
  if (ty == 0 && act) {
    float M = rm[0][tx];
#pragma unroll
    for (int q = 1; q < 4; q++) M = fmaxf(M, rm[q][tx]);
    float L = 0.f;
#pragma unroll
    for (int q = 0; q < 4; q++) L += rl[q][tx] * __expf(rm[q][tx] - M);
    float* st = statsOut + (size_t)b * T_ * S_;
    st[s] = M + __logf(L);                    // single fused stat
  }
}

// ---------------- alignment normalize: al = exp(raw - stat) --------------
__global__ __launch_bounds__(256)
void norm_kernel(float* __restrict__ al, const float* __restrict__ muStat)
{
  const int gid = blockIdx.x * 256 + threadIdx.x;
  if (gid >= NMU / 4) return;
  const int b   = gid / (T_ * S_ / 4);
  const int rem = gid - b * (T_ * S_ / 4);
  const int s4  = rem % (S_ / 4);
  const float4 st4 = *(const float4*)&muStat[(size_t)b * T_ * S_ + 4 * s4];
  float4 r = ((const float4*)al)[gid];
  float4 a;
  a.x = __expf(r.x - st4.x);
  a.y = __expf(r.y - st4.y);
  a.z = __expf(r.z - st4.z);
  a.w = __expf(r.w - st4.w);
  ((float4*)al)[gid] = a;
}

// ---------------- fused DP + mu/pi writeback (3 waves) -------------------
// Wave 0 (DP): self-DMAs al & mask rows into 8-row LDS rings (vmcnt FIFO =
// DMAs only, counted vmcnt(28) per step), interleaved lane layout
// (lane l owns s = l+64k -> all LDS b32 conflict-free), writes mu rows to a
// 16-slot LDS ring, publishes a monotone row counter. Waves 1,2 (writers):
// alternate rows; store mu row r to global AND compute+store pi row r+1
// (pi[t] depends only on mu[t-1]). pi_kernel eliminated.
__global__ __launch_bounds__(192, 1)
void dp_fused(const float* __restrict__ Al, const float* __restrict__ Mk,
              float* __restrict__ muOut, float* __restrict__ piOut)
{
  __shared__ float ar[8 * S_];     // al ring (12.8 KB)
  __shared__ float kr[8 * S_];     // mask ring (12.8 KB)
  __shared__ float mr[16 * S_];    // mu ring (25.6 KB)
  __shared__ int rowdone;
  __shared__ int wprog[2];

  const int b   = blockIdx.x;
  const int tid = threadIdx.x;
  const int wv  = tid >> 6;
  const int l   = tid & 63;

  if (tid == 0) rowdone = -1;
  if (tid < 2) wprog[tid] = -1;
  __syncthreads();

  const float* alb = Al + (size_t)b * T_ * S_;
  const float* mkb = Mk + (size_t)b * T_ * S_;
  float* mub = muOut + (size_t)b * T_ * S_;
  float* pib = piOut + (size_t)b * T_ * S_ * 2;

  volatile int* vrow = &rowdone;
  volatile int* vwp  = wprog;

  if (wv == 0) {
    // =============== DP wave ===============
    int cs[7];
#pragma unroll
    for (int k = 0; k < 6; k++) cs[k] = l + 64 * k;
    cs[6] = (l < 16) ? (384 + l) : 399;
    const bool a6 = (l < 16);

    float m[7], wa[7], wb2[7];

#define DMA2(ring, gbase, row)                                              \
  { const char* s_ = (const char*)((gbase) + (size_t)(row) * S_);           \
    char* d_ = (char*)(ring) + (((row) & 7) * 1600);                        \
    __builtin_amdgcn_global_load_lds(                                       \
      (const __attribute__((address_space(1))) void*)(s_ + l * 16),         \
      (__attribute__((address_space(3))) void*)(d_ + l * 16), 16, 0, 0);    \
    if (l < 36)                                                             \
      __builtin_amdgcn_global_load_lds(                                     \
        (const __attribute__((address_space(1))) void*)(s_ + 1024 + l*16),  \
        (__attribute__((address_space(3))) void*)(d_ + 1024 + l*16), 16, 0, 0); }

#define VMW(n) asm volatile("s_waitcnt vmcnt(" #n ")" ::: "memory");

#define RDROW(row, dst)                                                     \
  { const float* pa_ = ar + (((row) & 7) * S_);                             \
    const float* pk_ = kr + (((row) & 7) * S_);                             \
    _Pragma("unroll")                                                       \
    for (int k = 0; k < 7; k++) dst[k] = pa_[cs[k]] * pk_[cs[k]]; }

#define COMPROW(t, cur)                                                     \
  { float sf0[7], sfu[7];                                                   \
    sfu[0] = __shfl_up(m[0], 1); sf0[0] = NEGV;                             \
    _Pragma("unroll")                                                       \
    for (int k = 1; k < 7; k++) {                                           \
      sfu[k] = __shfl_up(m[k], 1);                                          \
      sf0[k] = __shfl(m[k - 1], 63);                                        \
    }                                                                       \
    _Pragma("unroll")                                                       \
    for (int k = 0; k < 7; k++) {                                           \
      float sft = (l == 0) ? sf0[k] : sfu[k];                               \
      float prev = m[k];                                                    \
      float d  = prev - sft;                                                \
      float e  = __expf(-fabsf(d));                                         \
      float lg = __logf(1.f + e);                                           \
      float hx = fmaxf(prev, sft);                                          \
      m[k] = cur[k] + hx + lg;                                              \
    }                                                                       \
    float* mw_ = mr + (((t) & 15) * S_);                                    \
    _Pragma("unroll")                                                       \
    for (int k = 0; k < 6; k++) mw_[cs[k]] = m[k];                          \
    if (a6) mw_[cs[6]] = m[6]; }

#define PUBLISH(t)                                                          \
  { asm volatile("s_waitcnt lgkmcnt(0)" ::: "memory");                      \
    *vrow = (t); }

#define STEPM(t, CUR, NXT)                                                  \
  { PUBLISH((t) - 1)                                                        \
    if (((t) & 7) == 0) {                                                   \
      for (;;) { int w0_ = vwp[0], w1_ = vwp[1];                            \
                 int mn_ = (w0_ < w1_) ? w0_ : w1_;                         \
                 if (mn_ >= (t) - 9) break; }                               \
      asm volatile("" ::: "memory");                                        \
    }                                                                       \
    DMA2(ar, alb, (t) + 8) DMA2(kr, mkb, (t) + 8)                           \
    VMW(28)                                                                 \
    RDROW((t) + 1, NXT)                                                     \
    COMPROW(t, CUR) }

#define STEPT(t, CUR, NXT, VN)                                              \
  { PUBLISH((t) - 1)                                                        \
    VMW(VN)                                                                 \
    RDROW((t) + 1, NXT)                                                     \
    COMPROW(t, CUR) }

    // prologue: DMA rows 0..7, base case on row 0, pre-read row 1
#pragma unroll
    for (int r = 0; r < 8; r++) { DMA2(ar, alb, r) DMA2(kr, mkb, r) }
    VMW(28)
    RDROW(0, wa)
#pragma unroll
    for (int k = 0; k < 7; k++) m[k] = wa[k] + ((k == 0 && l == 0) ? 0.f : NEGV);
    {
      float* mw_ = mr;
#pragma unroll
      for (int k = 0; k < 6; k++) mw_[cs[k]] = m[k];
      if (a6) mw_[cs[6]] = m[6];
    }
    DMA2(ar, alb, 8) DMA2(kr, mkb, 8)
    VMW(28)
    RDROW(1, wb2)

    for (int t = 1; t <= 1989; t += 2) {
      STEPM(t, wb2, wa)
      STEPM(t + 1, wa, wb2)
    }
    STEPM(1991, wb2, wa)
    STEPT(1992, wa, wb2, 24)
    STEPT(1993, wb2, wa, 20)
    STEPT(1994, wa, wb2, 16)
    STEPT(1995, wb2, wa, 12)
    STEPT(1996, wa, wb2, 8)
    STEPT(1997, wb2, wa, 4)
    STEPT(1998, wa, wb2, 0)
    PUBLISH(1998)
    COMPROW(1999, wb2)
    PUBLISH(1999)

#undef DMA2
#undef VMW
#undef RDROW
#undef COMPROW
#undef PUBLISH
#undef STEPM
#undef STEPT
  } else {
    // =============== writer waves (wv = 1, 2) ===============
    const int wid = wv - 1;
    const int c0  = (l < 50) ? l * 8 : 392;
    const bool act = (l < 50);

    if (wid == 0 && act) {            // pi row 0 = (1,0)
      float* p0_ = pib + 2 * c0;
#pragma unroll
      for (int q = 0; q < 4; q++)
        *(float4*)&p0_[4 * q] = make_float4(1.f, 0.f, 1.f, 0.f);
    }

    for (int r = wid; r < T_; r += 2) {
      while (*vrow < r) {}
      asm volatile("" ::: "memory");
      const float* mrow = mr + ((r & 15) * S_);
      float4 lo = *(const float4*)&mrow[c0];
      float4 hi = *(const float4*)&mrow[c0 + 4];
      float left = (c0 == 0) ? NEGV : mrow[c0 - 1];
      if (act) {
        float* mw = mub + (size_t)r * S_ + c0;
        *(float4*)mw       = lo;
        *(float4*)(mw + 4) = hi;
      }
      if (act && r < T_ - 1) {
        float pv[8] = {lo.x, lo.y, lo.z, lo.w, hi.x, hi.y, hi.z, hi.w};
        float sf[8] = {left, lo.x, lo.y, lo.z, lo.w, hi.x, hi.y, hi.z};
        float o[16];
#pragma unroll
        for (int i = 0; i < 8; i++) {
          float d = pv[i] - sf[i];
          float e = __expf(-fabsf(d));
          float q = 1.f + e;
          float rc;
          asm("v_rcp_f32 %0, %1" : "=v"(rc) : "v"(q));
          float rr = (d >= 0.f) ? rc : 1.f - rc;
          o[2 * i] = rr; o[2 * i + 1] = 1.f - rr;
        }
        float* pw = pib + (size_t)(r + 1) * (2 * S_) + 2 * c0;
#pragma unroll
        for (int q = 0; q < 4; q++)
          *(float4*)&pw[4 * q] = make_float4(o[4*q], o[4*q+1], o[4*q+2], o[4*q+3]);
      }
      asm volatile("s_waitcnt lgkmcnt(0)" ::: "memory");
      vwp[wid] = r;
    }
  }
}

// -------------------------------------------------------------------------
extern "C" void kernel_launch(void* const* d_in, const int* in_sizes, int n_in,
                              void* d_out, int out_size, void* d_ws, size_t ws_size,
                              hipStream_t stream)
{
  (void)in_sizes; (void)n_in; (void)out_size; (void)d_ws; (void)ws_size;
  const float* x   = (const float*)d_in[0];
  const float* enc = (const float*)d_in[1];
  const float* msk = (const float*)d_in[2];
  const float* w1  = (const float*)d_in[3];
  const float* b1  = (const float*)d_in[4];
  const float* w2  = (const float*)d_in[5];
  const float* b2  = (const float*)d_in[6];
  const float* w3  = (const float*)d_in[7];
  const float* b3  = (const float*)d_in[8];

  float* out = (float*)d_out;
  float* mu  = out;                       // [B,T,S]
  float* pi  = out + NMU;                 // [B,T,S,2]
  float* al  = out + NMU + NPI;           // [B,T,S]
  float* wsp = out + NMU + NPI + NMU;     // [B,T,H] fp32

  // conv scratch inside pi region (consumed before dp_fused writes pi)
  _Float16*  h1  = (_Float16*)(pi + 26000000);       // 16.384M halves
  _Float16*  h2  = (_Float16*)(pi + 35000000);       // 16.384M halves
  _Float16*  wc1 = (_Float16*)(pi + 44000000);
  _Float16*  wc2 = (_Float16*)(pi + 44100000);
  _Float16*  wc3 = (_Float16*)(pi + 44300000);

  hipLaunchKernelGGL(wprep, dim3((256*5*96 +255)/256), dim3(256), 0, stream, w1, wc1, C0_, 96);
  hipLaunchKernelGGL(wprep, dim3((256*5*256+255)/256), dim3(256), 0, stream, w2, wc2, H_, 256);
  hipLaunchKernelGGL(wprep, dim3((256*5*256+255)/256), dim3(256), 0, stream, w3, wc3, H_, 256);

  dim3 cgrid((T_ + 63) / 64, B_);
  hipLaunchKernelGGL((conv_mfma<C0_,  96, true,  false>), cgrid, dim3(256), 0, stream,
                     (const void*)x,  wc1, b1, (void*)h1);
  hipLaunchKernelGGL((conv_mfma<H_,  256, false, false>), cgrid, dim3(256), 0, stream,
                     (const void*)h1, wc2, b2, (void*)h2);
  hipLaunchKernelGGL((conv_mfma<H_,  256, false, true >), cgrid, dim3(256), 0, stream,
                     (const void*)h2, wc3, b3, (void*)wsp);

  hipLaunchKernelGGL(einsum_ts, dim3((T_ + 127) / 128, (S_ + 63) / 64, B_), dim3(256),
                     0, stream, wsp, enc, al);
  hipLaunchKernelGGL(softmax_stats, dim3((S_ + 63) / 64, B_), dim3(256), 0, stream, al, mu);
  hipLaunchKernelGGL(norm_kernel, dim3(NMU / 4 / 256), dim3(256), 0, stream, al, mu);
  hipLaunchKernelGGL(dp_fused, dim3(B_), dim3(192), 0, stream, al, msk, mu, pi);
}

// Round 13
// 2470.376 us; speedup vs baseline: 1.0956x; 1.0956x over previous
//
#include <hip/hip_runtime.h>
#include <hip/hip_bf16.h>

#define B_ 32
#define T_ 2000
#define S_ 400
#define C0_ 80
#define H_ 256

static constexpr float NEGV = -1e9f;
static constexpr int NMU  = B_ * T_ * S_;       // 25,600,000
static constexpr int NPI  = 2 * NMU;            // 51,200,000

typedef _Float16 f16x8 __attribute__((ext_vector_type(8)));
typedef float    f32x4 __attribute__((ext_vector_type(4)));

// ---------------- weight repack: wcat[co][k*CPAD+ci] = w[k][ci][co] ------
__global__ __launch_bounds__(256)
void wprep(const float* __restrict__ w, _Float16* __restrict__ wcat,
           int CIN, int CPAD)
{
  const int tot = 256 * 5 * CPAD;
  int idx = blockIdx.x * 256 + threadIdx.x;
  if (idx >= tot) return;
  int co  = idx / (5 * CPAD);
  int rem = idx - co * (5 * CPAD);
  int k   = rem / CPAD;
  int ci  = rem - k * CPAD;
  float v = (ci < CIN) ? w[((size_t)k * CIN + ci) * H_ + co] : 0.f;
  wcat[idx] = (_Float16)v;
}

// ---------------- conv1d (K=5, SAME) + bias + tanh via f16 MFMA ----------
template<int CIN, int CPAD, bool INF32, bool OUTF32>
__global__ __launch_bounds__(256)
void conv_mfma(const void* __restrict__ xin, const _Float16* __restrict__ wcat,
               const float* __restrict__ bias, void* __restrict__ yout)
{
  constexpr int KK  = 5 * CPAD;      // 480 / 1280
  constexpr int NS  = KK / 32;       // 15 / 40
  constexpr int STR = CPAD + 8;      // LDS row stride
  __shared__ _Float16 xs[68 * STR];
  const int b   = blockIdx.y;
  const int t0  = blockIdx.x * 64;
  const int tid = threadIdx.x;
  const int w   = tid >> 6;
  const int l   = tid & 63;

  if constexpr (INF32) {
    const float* xb = (const float*)xin + (size_t)b * T_ * CIN;
    constexpr int NG = CPAD / 4;
    for (int idx = tid; idx < 68 * NG; idx += 256) {
      int j = idx / NG, g = idx - j * NG;
      int t = t0 - 2 + j;
      int c = g * 4;
      float4 v = make_float4(0.f, 0.f, 0.f, 0.f);
      if (t >= 0 && t < T_ && c < CIN) v = *(const float4*)&xb[(size_t)t * CIN + c];
      _Float16* d = &xs[j * STR + c];
      d[0] = (_Float16)v.x; d[1] = (_Float16)v.y;
      d[2] = (_Float16)v.z; d[3] = (_Float16)v.w;
    }
  } else {
    const _Float16* xb = (const _Float16*)xin + (size_t)b * T_ * CIN;
    constexpr int NG = CPAD / 8;
    for (int idx = tid; idx < 68 * NG; idx += 256) {
      int j = idx / NG, g = idx - j * NG;
      int t = t0 - 2 + j;
      f16x8 v = {(_Float16)0,(_Float16)0,(_Float16)0,(_Float16)0,
                 (_Float16)0,(_Float16)0,(_Float16)0,(_Float16)0};
      if (t >= 0 && t < T_) v = *(const f16x8*)&xb[(size_t)t * CIN + g * 8];
      *(f16x8*)&xs[j * STR + g * 8] = v;
    }
  }
  __syncthreads();

  const int lr = l & 15;
  const int lk = (l >> 4) * 8;

  f32x4 acc[4][4];
  const f32x4 zz = {0.f, 0.f, 0.f, 0.f};
#pragma unroll
  for (int i = 0; i < 4; i++)
#pragma unroll
    for (int j = 0; j < 4; j++) acc[i][j] = zz;

  const _Float16* wbase = wcat + (size_t)(w * 64 + lr) * KK + lk;

  for (int kk = 0; kk < NS; kk++) {
    const int p  = kk * 32;
    const int k  = p / CPAD;
    const int ci = p - k * CPAD;
    f16x8 a0 = *(const f16x8*)&xs[( 0 + lr + k) * STR + ci + lk];
    f16x8 a1 = *(const f16x8*)&xs[(16 + lr + k) * STR + ci + lk];
    f16x8 a2 = *(const f16x8*)&xs[(32 + lr + k) * STR + ci + lk];
    f16x8 a3 = *(const f16x8*)&xs[(48 + lr + k) * STR + ci + lk];
    f16x8 w0 = *(const f16x8*)&wbase[(size_t)( 0) * KK + p];
    f16x8 w1 = *(const f16x8*)&wbase[(size_t)(16) * KK + p];
    f16x8 w2 = *(const f16x8*)&wbase[(size_t)(32) * KK + p];
    f16x8 w3 = *(const f16x8*)&wbase[(size_t)(48) * KK + p];
    acc[0][0] = __builtin_amdgcn_mfma_f32_16x16x32_f16(a0, w0, acc[0][0], 0, 0, 0);
    acc[0][1] = __builtin_amdgcn_mfma_f32_16x16x32_f16(a0, w1, acc[0][1], 0, 0, 0);
    acc[0][2] = __builtin_amdgcn_mfma_f32_16x16x32_f16(a0, w2, acc[0][2], 0, 0, 0);
    acc[0][3] = __builtin_amdgcn_mfma_f32_16x16x32_f16(a0, w3, acc[0][3], 0, 0, 0);
    acc[1][0] = __builtin_amdgcn_mfma_f32_16x16x32_f16(a1, w0, acc[1][0], 0, 0, 0);
    acc[1][1] = __builtin_amdgcn_mfma_f32_16x16x32_f16(a1, w1, acc[1][1], 0, 0, 0);
    acc[1][2] = __builtin_amdgcn_mfma_f32_16x16x32_f16(a1, w2, acc[1][2], 0, 0, 0);
    acc[1][3] = __builtin_amdgcn_mfma_f32_16x16x32_f16(a1, w3, acc[1][3], 0, 0, 0);
    acc[2][0] = __builtin_amdgcn_mfma_f32_16x16x32_f16(a2, w0, acc[2][0], 0, 0, 0);
    acc[2][1] = __builtin_amdgcn_mfma_f32_16x16x32_f16(a2, w1, acc[2][1], 0, 0, 0);
    acc[2][2] = __builtin_amdgcn_mfma_f32_16x16x32_f16(a2, w2, acc[2][2], 0, 0, 0);
    acc[2][3] = __builtin_amdgcn_mfma_f32_16x16x32_f16(a2, w3, acc[2][3], 0, 0, 0);
    acc[3][0] = __builtin_amdgcn_mfma_f32_16x16x32_f16(a3, w0, acc[3][0], 0, 0, 0);
    acc[3][1] = __builtin_amdgcn_mfma_f32_16x16x32_f16(a3, w1, acc[3][1], 0, 0, 0);
    acc[3][2] = __builtin_amdgcn_mfma_f32_16x16x32_f16(a3, w2, acc[3][2], 0, 0, 0);
    acc[3][3] = __builtin_amdgcn_mfma_f32_16x16x32_f16(a3, w3, acc[3][3], 0, 0, 0);
  }

#pragma unroll
  for (int ct = 0; ct < 4; ct++) {
    const int co = w * 64 + ct * 16 + lr;
    const float bv = bias[co];
#pragma unroll
    for (int tt = 0; tt < 4; tt++) {
#pragma unroll
      for (int r = 0; r < 4; r++) {
        const int t = t0 + tt * 16 + (l >> 4) * 4 + r;
        if (t < T_) {
          float v = tanhf(acc[tt][ct][r] + bv);
          if constexpr (OUTF32)
            ((float*)yout)[((size_t)b * T_ + t) * H_ + co] = v;
          else
            ((_Float16*)yout)[((size_t)b * T_ + t) * H_ + co] = (_Float16)v;
        }
      }
    }
  }
}

// ---------------- W[b,t,s] = sum_h Wspec[b,t,h] * src_enc[b,s,h] --------
__global__ __launch_bounds__(256)
void einsum_ts(const float* __restrict__ A, const float* __restrict__ E,
               float* __restrict__ Wg)
{
  constexpr int GT = 128, GS = 64, KC = 16;
  __shared__ float As[KC][GT + 4];
  __shared__ float Bs[KC][GS + 4];
  const int b   = blockIdx.z;
  const int t0  = blockIdx.x * GT;
  const int s0  = blockIdx.y * GS;
  const int tid = threadIdx.x;
  const int tx  = tid & 15;
  const int ty  = tid >> 4;
  float4 acc[8];
#pragma unroll
  for (int i = 0; i < 8; i++) acc[i] = make_float4(0.f, 0.f, 0.f, 0.f);
  const float* Ab = A + (size_t)b * T_ * H_;
  const float* Eb = E + (size_t)b * S_ * H_;
  for (int kc = 0; kc < H_; kc += KC) {
#pragma unroll
    for (int r = 0; r < 2; r++) {
      int f4  = tid + 256 * r;
      int row = f4 >> 2;
      int c4  = f4 & 3;
      int t   = t0 + row;
      float4 v = make_float4(0, 0, 0, 0);
      if (t < T_) v = *(const float4*)&Ab[(size_t)t * H_ + kc + c4 * 4];
      As[c4*4+0][row] = v.x; As[c4*4+1][row] = v.y;
      As[c4*4+2][row] = v.z; As[c4*4+3][row] = v.w;
    }
    {
      int row = tid >> 2;
      int c4  = tid & 3;
      int s   = s0 + row;
      float4 v = make_float4(0, 0, 0, 0);
      if (s < S_) v = *(const float4*)&Eb[(size_t)s * H_ + kc + c4 * 4];
      Bs[c4*4+0][row] = v.x; Bs[c4*4+1][row] = v.y;
      Bs[c4*4+2][row] = v.z; Bs[c4*4+3][row] = v.w;
    }
    __syncthreads();
#pragma unroll
    for (int kk = 0; kk < KC; kk++) {
      float4 a0 = *(const float4*)&As[kk][ty * 8];
      float4 a1 = *(const float4*)&As[kk][ty * 8 + 4];
      float4 bb = *(const float4*)&Bs[kk][tx * 4];
      float av[8] = {a0.x, a0.y, a0.z, a0.w, a1.x, a1.y, a1.z, a1.w};
#pragma unroll
      for (int i = 0; i < 8; i++) {
        acc[i].x = fmaf(av[i], bb.x, acc[i].x);
        acc[i].y = fmaf(av[i], bb.y, acc[i].y);
        acc[i].z = fmaf(av[i], bb.z, acc[i].z);
        acc[i].w = fmaf(av[i], bb.w, acc[i].w);
      }
    }
    __syncthreads();
  }
  float* Wb = Wg + (size_t)b * T_ * S_;
  const int s = s0 + tx * 4;
#pragma unroll
  for (int i = 0; i < 8; i++) {
    int t = t0 + ty * 8 + i;
    if (t < T_ && s < S_) *(float4*)&Wb[(size_t)t * S_ + s] = acc[i];
  }
}

// ---------------- per-(b,s) column softmax stats over T ------------------
__global__ __launch_bounds__(256)
void softmax_stats(const float* __restrict__ Wg, float* __restrict__ statsOut)
{
  const int b  = blockIdx.y;
  const int tx = threadIdx.x & 63;
  const int ty = threadIdx.x >> 6;            // 0..3
  const int s  = blockIdx.x * 64 + tx;
  const bool act = (s < S_);
  float m = -1e30f, l = 0.f;
  if (act) {
    const float* col = Wg + (size_t)b * T_ * S_ + s;
#pragma unroll 4
    for (int t = ty; t < T_; t += 4) {
      float v  = col[(size_t)t * S_];
      float nm = fmaxf(m, v);
      l = l * __expf(m - nm) + __expf(v - nm);
      m = nm;
    }
  }
  __shared__ float rm[4][64], rl[4][64];
  rm[ty][tx] = m; rl[ty][tx] = l;
  __syncthreads();
  if (ty == 0 && act) {
    float M = rm[0][tx];
#pragma unroll
    for (int q = 1; q < 4; q++) M = fmaxf(M, rm[q][tx]);
    float L = 0.f;
#pragma unroll
    for (int q = 0; q < 4; q++) L += rl[q][tx] * __expf(rm[q][tx] - M);
    float* st = statsOut + (size_t)b * T_ * S_;
    st[s] = M + __logf(L);                    // single fused stat
  }
}

// ---------------- alignment normalize: al = exp(raw - stat) --------------
__global__ __launch_bounds__(256)
void norm_kernel(float* __restrict__ al, const float* __restrict__ muStat)
{
  const int gid = blockIdx.x * 256 + threadIdx.x;
  if (gid >= NMU / 4) return;
  const int b   = gid / (T_ * S_ / 4);
  const int rem = gid - b * (T_ * S_ / 4);
  const int s4  = rem % (S_ / 4);
  const float4 st4 = *(const float4*)&muStat[(size_t)b * T_ * S_ + 4 * s4];
  float4 r = ((const float4*)al)[gid];
  float4 a;
  a.x = __expf(r.x - st4.x);
  a.y = __expf(r.y - st4.y);
  a.z = __expf(r.z - st4.z);
  a.w = __expf(r.w - st4.w);
  ((float4*)al)[gid] = a;
}

// ---------------- fused DP + mu/pi writeback (3 waves) -------------------
// Wave 0 (DP): self-DMAs al & mask rows into 8-row LDS rings (vmcnt FIFO =
// DMAs only, counted vmcnt(28)), interleaved lane layout (lane l owns
// s=l+64k -> all LDS b32 stride-1, conflict-free), writes mu rows to a
// 16-slot LDS ring, publishes a monotone row counter EVERY 4 STEPS.
// Waves 1,2 (writers): groups of 4 rows, interleaved b32 LDS reads +
// coalesced dword/dwordx2 global stores of mu and pi (pi[t] from mu[t-1]),
// one poll + one fence per group. Loose throttle (mr ring lag 13).
__global__ __launch_bounds__(192, 1)
void dp_fused(const float* __restrict__ Al, const float* __restrict__ Mk,
              float* __restrict__ muOut, float* __restrict__ piOut)
{
  __shared__ float ar[8 * S_];     // al ring (12.8 KB)
  __shared__ float kr[8 * S_];     // mask ring (12.8 KB)
  __shared__ float mr[16 * S_];    // mu ring (25.6 KB)
  __shared__ int rowdone;
  __shared__ int wprog[2];

  const int b   = blockIdx.x;
  const int tid = threadIdx.x;
  const int wv  = tid >> 6;
  const int l   = tid & 63;

  if (tid == 0) rowdone = -1;
  if (tid < 2) wprog[tid] = -1;
  __syncthreads();

  const float* alb = Al + (size_t)b * T_ * S_;
  const float* mkb = Mk + (size_t)b * T_ * S_;
  float* mub = muOut + (size_t)b * T_ * S_;
  float* pib = piOut + (size_t)b * T_ * S_ * 2;

  volatile int* vrow = &rowdone;
  volatile int* vwp  = wprog;

  int cs[7];
#pragma unroll
  for (int k = 0; k < 6; k++) cs[k] = l + 64 * k;
  const bool a6 = (l < 16);
  cs[6] = a6 ? (384 + l) : 399;

  if (wv == 0) {
    // =============== DP wave ===============
    float m[7], wa[7], wb2[7];

#define DMA2(ring, gbase, row)                                              \
  { const char* s_ = (const char*)((gbase) + (size_t)(row) * S_);           \
    char* d_ = (char*)(ring) + (((row) & 7) * 1600);                        \
    __builtin_amdgcn_global_load_lds(                                       \
      (const __attribute__((address_space(1))) void*)(s_ + l * 16),         \
      (__attribute__((address_space(3))) void*)(d_ + l * 16), 16, 0, 0);    \
    if (l < 36)                                                             \
      __builtin_amdgcn_global_load_lds(                                     \
        (const __attribute__((address_space(1))) void*)(s_ + 1024 + l*16),  \
        (__attribute__((address_space(3))) void*)(d_ + 1024 + l*16), 16, 0, 0); }

#define VMW(n) asm volatile("s_waitcnt vmcnt(" #n ")" ::: "memory");

#define RDROW(row, dst)                                                     \
  { const float* pa_ = ar + (((row) & 7) * S_);                             \
    const float* pk_ = kr + (((row) & 7) * S_);                             \
    _Pragma("unroll")                                                       \
    for (int k = 0; k < 7; k++) dst[k] = pa_[cs[k]] * pk_[cs[k]]; }

#define COMPROW(t, cur)                                                     \
  { float sf0[7], sfu[7];                                                   \
    sfu[0] = __shfl_up(m[0], 1); sf0[0] = NEGV;                             \
    _Pragma("unroll")                                                       \
    for (int k = 1; k < 7; k++) {                                           \
      sfu[k] = __shfl_up(m[k], 1);                                          \
      sf0[k] = __shfl(m[k - 1], 63);                                        \
    }                                                                       \
    _Pragma("unroll")                                                       \
    for (int k = 0; k < 7; k++) {                                           \
      float sft = (l == 0) ? sf0[k] : sfu[k];                               \
      float prev = m[k];                                                    \
      float d  = prev - sft;                                                \
      float e  = __expf(-fabsf(d));                                         \
      float lg = __logf(1.f + e);                                           \
      float hx = fmaxf(prev, sft);                                          \
      m[k] = cur[k] + hx + lg;                                              \
    }                                                                       \
    float* mw_ = mr + (((t) & 15) * S_);                                    \
    _Pragma("unroll")                                                       \
    for (int k = 0; k < 6; k++) mw_[cs[k]] = m[k];                          \
    if (a6) mw_[cs[6]] = m[6]; }

#define PUBLISH(t)                                                          \
  { asm volatile("s_waitcnt lgkmcnt(0)" ::: "memory");                      \
    *vrow = (t); }

#define THROTTLE(t)                                                         \
  { for (;;) { int w0_ = vwp[0], w1_ = vwp[1];                              \
               int mn_ = (w0_ < w1_) ? w0_ : w1_;                           \
               if (mn_ >= (t) - 13) break; }                                \
    asm volatile("" ::: "memory"); }

#define STEPM(t, CUR, NXT)                                                  \
  { DMA2(ar, alb, (t) + 8) DMA2(kr, mkb, (t) + 8)                           \
    VMW(28)                                                                 \
    RDROW((t) + 1, NXT)                                                     \
    COMPROW(t, CUR) }

#define STEPT(t, CUR, NXT, VN)                                              \
  { VMW(VN)                                                                 \
    RDROW((t) + 1, NXT)                                                     \
    COMPROW(t, CUR) }

    // prologue: DMA rows 0..7, base case on row 0, pre-read row 1
#pragma unroll
    for (int r = 0; r < 8; r++) { DMA2(ar, alb, r) DMA2(kr, mkb, r) }
    VMW(28)
    RDROW(0, wa)
#pragma unroll
    for (int k = 0; k < 7; k++) m[k] = wa[k] + ((k == 0 && l == 0) ? 0.f : NEGV);
    {
      float* mw_ = mr;
#pragma unroll
      for (int k = 0; k < 6; k++) mw_[cs[k]] = m[k];
      if (a6) mw_[cs[6]] = m[6];
    }
    DMA2(ar, alb, 8) DMA2(kr, mkb, 8)
    VMW(28)
    RDROW(1, wb2)

    // main: groups of 4 steps; publish + throttle once per group
    for (int t = 1; t <= 1985; t += 4) {
      PUBLISH(t - 1)
      THROTTLE(t)
      STEPM(t,     wb2, wa)
      STEPM(t + 1, wa, wb2)
      STEPM(t + 2, wb2, wa)
      STEPM(t + 3, wa, wb2)
    }
    // tail: steps 1989..1999 (last DMA row 1999 at step 1991)
    PUBLISH(1988) THROTTLE(1989)
    STEPM(1989, wb2, wa)
    STEPM(1990, wa, wb2)
    STEPM(1991, wb2, wa)
    STEPT(1992, wa, wb2, 24)
    PUBLISH(1992) THROTTLE(1993)
    STEPT(1993, wb2, wa, 20)
    STEPT(1994, wa, wb2, 16)
    STEPT(1995, wb2, wa, 12)
    STEPT(1996, wa, wb2, 8)
    PUBLISH(1996) THROTTLE(1997)
    STEPT(1997, wb2, wa, 4)
    STEPT(1998, wa, wb2, 0)
    COMPROW(1999, wb2)
    PUBLISH(1999)

#undef DMA2
#undef VMW
#undef RDROW
#undef COMPROW
#undef PUBLISH
#undef THROTTLE
#undef STEPM
#undef STEPT
  } else {
    // =============== writer waves (wv = 1, 2) ===============
    const int wid = wv - 1;

    if (wid == 0) {                   // pi row 0 = (1,0), coalesced dwordx2
#pragma unroll
      for (int k = 0; k < 6; k++)
        *(float2*)&pib[2 * cs[k]] = make_float2(1.f, 0.f);
      if (a6) *(float2*)&pib[2 * cs[6]] = make_float2(1.f, 0.f);
    }

    for (int g = wid; g < 500; g += 2) {
      const int rend = 4 * g + 3;
      while (*vrow < rend) {}
      asm volatile("" ::: "memory");
#pragma unroll
      for (int rr = 0; rr < 4; rr++) {
        const int r = 4 * g + rr;
        const float* mrow = mr + ((r & 15) * S_);
        float v[7];
#pragma unroll
        for (int k = 0; k < 7; k++) v[k] = mrow[cs[k]];   // b32 stride-1
        float* mw = mub + (size_t)r * S_;
#pragma unroll
        for (int k = 0; k < 6; k++) mw[cs[k]] = v[k];     // coalesced dword
        if (a6) mw[cs[6]] = v[6];
        if (r < T_ - 1) {                                 // pi row r+1
          float* pw = pib + (size_t)(r + 1) * (2 * S_);
#pragma unroll
          for (int k = 0; k < 7; k++) {
            float shv = __shfl_up(v[k], 1);
            float b0  = (k == 0) ? NEGV : __shfl(v[k - 1], 63);
            float sft = (l == 0) ? b0 : shv;
            float d = v[k] - sft;
            float e = __expf(-fabsf(d));
            float q = 1.f + e;
            float rc;
            asm("v_rcp_f32 %0, %1" : "=v"(rc) : "v"(q));
            float rr2 = (d >= 0.f) ? rc : 1.f - rc;
            if (k < 6 || a6)
              *(float2*)&pw[2 * cs[k]] = make_float2(rr2, 1.f - rr2);
          }
        }
      }
      asm volatile("s_waitcnt lgkmcnt(0)" ::: "memory");
      vwp[wid] = rend;
    }
  }
}

// -------------------------------------------------------------------------
extern "C" void kernel_launch(void* const* d_in, const int* in_sizes, int n_in,
                              void* d_out, int out_size, void* d_ws, size_t ws_size,
                              hipStream_t stream)
{
  (void)in_sizes; (void)n_in; (void)out_size; (void)d_ws; (void)ws_size;
  const float* x   = (const float*)d_in[0];
  const float* enc = (const float*)d_in[1];
  const float* msk = (const float*)d_in[2];
  const float* w1  = (const float*)d_in[3];
  const float* b1  = (const float*)d_in[4];
  const float* w2  = (const float*)d_in[5];
  const float* b2  = (const float*)d_in[6];
  const float* w3  = (const float*)d_in[7];
  const float* b3  = (const float*)d_in[8];

  float* out = (float*)d_out;
  float* mu  = out;                       // [B,T,S]
  float* pi  = out + NMU;                 // [B,T,S,2]
  float* al  = out + NMU + NPI;           // [B,T,S]
  float* wsp = out + NMU + NPI + NMU;     // [B,T,H] fp32

  // conv scratch inside pi region (consumed before dp_fused writes pi)
  _Float16*  h1  = (_Float16*)(pi + 26000000);       // 16.384M halves
  _Float16*  h2  = (_Float16*)(pi + 35000000);       // 16.384M halves
  _Float16*  wc1 = (_Float16*)(pi + 44000000);
  _Float16*  wc2 = (_Float16*)(pi + 44100000);
  _Float16*  wc3 = (_Float16*)(pi + 44300000);

  hipLaunchKernelGGL(wprep, dim3((256*5*96 +255)/256), dim3(256), 0, stream, w1, wc1, C0_, 96);
  hipLaunchKernelGGL(wprep, dim3((256*5*256+255)/256), dim3(256), 0, stream, w2, wc2, H_, 256);
  hipLaunchKernelGGL(wprep, dim3((256*5*256+255)/256), dim3(256), 0, stream, w3, wc3, H_, 256);

  dim3 cgrid((T_ + 63) / 64, B_);
  hipLaunchKernelGGL((conv_mfma<C0_,  96, true,  false>), cgrid, dim3(256), 0, stream,
                     (const void*)x,  wc1, b1, (void*)h1);
  hipLaunchKernelGGL((conv_mfma<H_,  256, false, false>), cgrid, dim3(256), 0, stream,
                     (const void*)h1, wc2, b2, (void*)h2);
  hipLaunchKernelGGL((conv_mfma<H_,  256, false, true >), cgrid, dim3(256), 0, stream,
                     (const void*)h2, wc3, b3, (void*)wsp);

  hipLaunchKernelGGL(einsum_ts, dim3((T_ + 127) / 128, (S_ + 63) / 64, B_), dim3(256),
                     0, stream, wsp, enc, al);
  hipLaunchKernelGGL(softmax_stats, dim3((S_ + 63) / 64, B_), dim3(256), 0, stream, al, mu);
  hipLaunchKernelGGL(norm_kernel, dim3(NMU / 4 / 256), dim3(256), 0, stream, al, mu);
  hipLaunchKernelGGL(dp_fused, dim3(B_), dim3(192), 0, stream, al, msk, mu, pi);
}

// Round 14
// 1282.839 us; speedup vs baseline: 2.1098x; 1.9257x over previous
//
#include <hip/hip_runtime.h>
#include <hip/hip_bf16.h>

#define B_ 32
#define T_ 2000
#define S_ 400
#define C0_ 80
#define H_ 256

static constexpr float NEGV = -1e9f;
static constexpr int NMU  = B_ * T_ * S_;       // 25,600,000
static constexpr int NPI  = 2 * NMU;            // 51,200,000

typedef _Float16 f16x8 __attribute__((ext_vector_type(8)));
typedef float    f32x4 __attribute__((ext_vector_type(4)));

// ---------------- weight repack: wcat[co][k*CPAD+ci] = w[k][ci][co] ------
__global__ __launch_bounds__(256)
void wprep(const float* __restrict__ w, _Float16* __restrict__ wcat,
           int CIN, int CPAD)
{
  const int tot = 256 * 5 * CPAD;
  int idx = blockIdx.x * 256 + threadIdx.x;
  if (idx >= tot) return;
  int co  = idx / (5 * CPAD);
  int rem = idx - co * (5 * CPAD);
  int k   = rem / CPAD;
  int ci  = rem - k * CPAD;
  float v = (ci < CIN) ? w[((size_t)k * CIN + ci) * H_ + co] : 0.f;
  wcat[idx] = (_Float16)v;
}

// ---------------- conv1d (K=5, SAME) + bias + tanh via f16 MFMA ----------
template<int CIN, int CPAD, bool INF32, bool OUTF32>
__global__ __launch_bounds__(256)
void conv_mfma(const void* __restrict__ xin, const _Float16* __restrict__ wcat,
               const float* __restrict__ bias, void* __restrict__ yout)
{
  constexpr int KK  = 5 * CPAD;      // 480 / 1280
  constexpr int NS  = KK / 32;       // 15 / 40
  constexpr int STR = CPAD + 8;      // LDS row stride
  __shared__ _Float16 xs[68 * STR];
  const int b   = blockIdx.y;
  const int t0  = blockIdx.x * 64;
  const int tid = threadIdx.x;
  const int w   = tid >> 6;
  const int l   = tid & 63;

  if constexpr (INF32) {
    const float* xb = (const float*)xin + (size_t)b * T_ * CIN;
    constexpr int NG = CPAD / 4;
    for (int idx = tid; idx < 68 * NG; idx += 256) {
      int j = idx / NG, g = idx - j * NG;
      int t = t0 - 2 + j;
      int c = g * 4;
      float4 v = make_float4(0.f, 0.f, 0.f, 0.f);
      if (t >= 0 && t < T_ && c < CIN) v = *(const float4*)&xb[(size_t)t * CIN + c];
      _Float16* d = &xs[j * STR + c];
      d[0] = (_Float16)v.x; d[1] = (_Float16)v.y;
      d[2] = (_Float16)v.z; d[3] = (_Float16)v.w;
    }
  } else {
    const _Float16* xb = (const _Float16*)xin + (size_t)b * T_ * CIN;
    constexpr int NG = CPAD / 8;
    for (int idx = tid; idx < 68 * NG; idx += 256) {
      int j = idx / NG, g = idx - j * NG;
      int t = t0 - 2 + j;
      f16x8 v = {(_Float16)0,(_Float16)0,(_Float16)0,(_Float16)0,
                 (_Float16)0,(_Float16)0,(_Float16)0,(_Float16)0};
      if (t >= 0 && t < T_) v = *(const f16x8*)&xb[(size_t)t * CIN + g * 8];
      *(f16x8*)&xs[j * STR + g * 8] = v;
    }
  }
  __syncthreads();

  const int lr = l & 15;
  const int lk = (l >> 4) * 8;

  f32x4 acc[4][4];
  const f32x4 zz = {0.f, 0.f, 0.f, 0.f};
#pragma unroll
  for (int i = 0; i < 4; i++)
#pragma unroll
    for (int j = 0; j < 4; j++) acc[i][j] = zz;

  const _Float16* wbase = wcat + (size_t)(w * 64 + lr) * KK + lk;

  for (int kk = 0; kk < NS; kk++) {
    const int p  = kk * 32;
    const int k  = p / CPAD;
    const int ci = p - k * CPAD;
    f16x8 a0 = *(const f16x8*)&xs[( 0 + lr + k) * STR + ci + lk];
    f16x8 a1 = *(const f16x8*)&xs[(16 + lr + k) * STR + ci + lk];
    f16x8 a2 = *(const f16x8*)&xs[(32 + lr + k) * STR + ci + lk];
    f16x8 a3 = *(const f16x8*)&xs[(48 + lr + k) * STR + ci + lk];
    f16x8 w0 = *(const f16x8*)&wbase[(size_t)( 0) * KK + p];
    f16x8 w1 = *(const f16x8*)&wbase[(size_t)(16) * KK + p];
    f16x8 w2 = *(const f16x8*)&wbase[(size_t)(32) * KK + p];
    f16x8 w3 = *(const f16x8*)&wbase[(size_t)(48) * KK + p];
    acc[0][0] = __builtin_amdgcn_mfma_f32_16x16x32_f16(a0, w0, acc[0][0], 0, 0, 0);
    acc[0][1] = __builtin_amdgcn_mfma_f32_16x16x32_f16(a0, w1, acc[0][1], 0, 0, 0);
    acc[0][2] = __builtin_amdgcn_mfma_f32_16x16x32_f16(a0, w2, acc[0][2], 0, 0, 0);
    acc[0][3] = __builtin_amdgcn_mfma_f32_16x16x32_f16(a0, w3, acc[0][3], 0, 0, 0);
    acc[1][0] = __builtin_amdgcn_mfma_f32_16x16x32_f16(a1, w0, acc[1][0], 0, 0, 0);
    acc[1][1] = __builtin_amdgcn_mfma_f32_16x16x32_f16(a1, w1, acc[1][1], 0, 0, 0);
    acc[1][2] = __builtin_amdgcn_mfma_f32_16x16x32_f16(a1, w2, acc[1][2], 0, 0, 0);
    acc[1][3] = __builtin_amdgcn_mfma_f32_16x16x32_f16(a1, w3, acc[1][3], 0, 0, 0);
    acc[2][0] = __builtin_amdgcn_mfma_f32_16x16x32_f16(a2, w0, acc[2][0], 0, 0, 0);
    acc[2][1] = __builtin_amdgcn_mfma_f32_16x16x32_f16(a2, w1, acc[2][1], 0, 0, 0);
    acc[2][2] = __builtin_amdgcn_mfma_f32_16x16x32_f16(a2, w2, acc[2][2], 0, 0, 0);
    acc[2][3] = __builtin_amdgcn_mfma_f32_16x16x32_f16(a2, w3, acc[2][3], 0, 0, 0);
    acc[3][0] = __builtin_amdgcn_mfma_f32_16x16x32_f16(a3, w0, acc[3][0], 0, 0, 0);
    acc[3][1] = __builtin_amdgcn_mfma_f32_16x16x32_f16(a3, w1, acc[3][1], 0, 0, 0);
    acc[3][2] = __builtin_amdgcn_mfma_f32_16x16x32_f16(a3, w2, acc[3][2], 0, 0, 0);
    acc[3][3] = __builtin_amdgcn_mfma_f32_16x16x32_f16(a3, w3, acc[3][3], 0, 0, 0);
  }

#pragma unroll
  for (int ct = 0; ct < 4; ct++) {
    const int co = w * 64 + ct * 16 + lr;
    const float bv = bias[co];
#pragma unroll
    for (int tt = 0; tt < 4; tt++) {
#pragma unroll
      for (int r = 0; r < 4; r++) {
        const int t = t0 + tt * 16 + (l >> 4) * 4 + r;
        if (t < T_) {
          float v = tanhf(acc[tt][ct][r] + bv);
          if constexpr (OUTF32)
            ((float*)yout)[((size_t)b * T_ + t) * H_ + co] = v;
          else
            ((_Float16*)yout)[((size_t)b * T_ + t) * H_ + co] = (_Float16)v;
        }
      }
    }
  }
}

// ---------------- W[b,t,s] = sum_h Wspec[b,t,h] * src_enc[b,s,h] --------
__global__ __launch_bounds__(256)
void einsum_ts(const float* __restrict__ A, const float* __restrict__ E,
               float* __restrict__ Wg)
{
  constexpr int GT = 128, GS = 64, KC = 16;
  __shared__ float As[KC][GT + 4];
  __shared__ float Bs[KC][GS + 4];
  const int b   = blockIdx.z;
  const int t0  = blockIdx.x * GT;
  const int s0  = blockIdx.y * GS;
  const int tid = threadIdx.x;
  const int tx  = tid & 15;
  const int ty  = tid >> 4;
  float4 acc[8];
#pragma unroll
  for (int i = 0; i < 8; i++) acc[i] = make_float4(0.f, 0.f, 0.f, 0.f);
  const float* Ab = A + (size_t)b * T_ * H_;
  const float* Eb = E + (size_t)b * S_ * H_;
  for (int kc = 0; kc < H_; kc += KC) {
#pragma unroll
    for (int r = 0; r < 2; r++) {
      int f4  = tid + 256 * r;
      int row = f4 >> 2;
      int c4  = f4 & 3;
      int t   = t0 + row;
      float4 v = make_float4(0, 0, 0, 0);
      if (t < T_) v = *(const float4*)&Ab[(size_t)t * H_ + kc + c4 * 4];
      As[c4*4+0][row] = v.x; As[c4*4+1][row] = v.y;
      As[c4*4+2][row] = v.z; As[c4*4+3][row] = v.w;
    }
    {
      int row = tid >> 2;
      int c4  = tid & 3;
      int s   = s0 + row;
      float4 v = make_float4(0, 0, 0, 0);
      if (s < S_) v = *(const float4*)&Eb[(size_t)s * H_ + kc + c4 * 4];
      Bs[c4*4+0][row] = v.x; Bs[c4*4+1][row] = v.y;
      Bs[c4*4+2][row] = v.z; Bs[c4*4+3][row] = v.w;
    }
    __syncthreads();
#pragma unroll
    for (int kk = 0; kk < KC; kk++) {
      float4 a0 = *(const float4*)&As[kk][ty * 8];
      float4 a1 = *(const float4*)&As[kk][ty * 8 + 4];
      float4 bb = *(const float4*)&Bs[kk][tx * 4];
      float av[8] = {a0.x, a0.y, a0.z, a0.w, a1.x, a1.y, a1.z, a1.w};
#pragma unroll
      for (int i = 0; i < 8; i++) {
        acc[i].x = fmaf(av[i], bb.x, acc[i].x);
        acc[i].y = fmaf(av[i], bb.y, acc[i].y);
        acc[i].z = fmaf(av[i], bb.z, acc[i].z);
        acc[i].w = fmaf(av[i], bb.w, acc[i].w);
      }
    }
    __syncthreads();
  }
  float* Wb = Wg + (size_t)b * T_ * S_;
  const int s = s0 + tx * 4;
#pragma unroll
  for (int i = 0; i < 8; i++) {
    int t = t0 + ty * 8 + i;
    if (t < T_ && s < S_) *(float4*)&Wb[(size_t)t * S_ + s] = acc[i];
  }
}

// ---------------- per-(b,s) column softmax stats over T ------------------
__global__ __launch_bounds__(256)
void softmax_stats(const float* __restrict__ Wg, float* __restrict__ statsOut)
{
  const int b  = blockIdx.y;
  const int tx = threadIdx.x & 63;
  const int ty = threadIdx.x >> 6;            // 0..3
  const int s  = blockIdx.x * 64 + tx;
  const bool act = (s < S_);
  float m = -1e30f, l = 0.f;
  if (act) {
    const float* col = Wg + (size_t)b * T_ * S_ + s;
#pragma unroll 4
    for (int t = ty; t < T_; t += 4) {
      float v  = col[(size_t)t * S_];
      float nm = fmaxf(m, v);
      l = l * __expf(m - nm) + __expf(v - nm);
      m = nm;
    }
  }
  __shared__ float rm[4][64], rl[4][64];
  rm[ty][tx] = m; rl[ty][tx] = l;
  __syncthreads();
  if (ty == 0 && act) {
    float M = rm[0][tx];
#pragma unroll
    for (int q = 1; q < 4; q++) M = fmaxf(M, rm[q][tx]);
    float L = 0.f;
#pragma unroll
    for (int q = 0; q < 4; q++) L += rl[q][tx] * __expf(rm[q][tx] - M);
    float* st = statsOut + (size_t)b * T_ * S_;
    st[s] = M + __logf(L);                    // single fused stat
  }
}

// ---------------- alignment normalize: al = exp(raw - stat) --------------
__global__ __launch_bounds__(256)
void norm_kernel(float* __restrict__ al, const float* __restrict__ muStat)
{
  const int gid = blockIdx.x * 256 + threadIdx.x;
  if (gid >= NMU / 4) return;
  const int b   = gid / (T_ * S_ / 4);
  const int rem = gid - b * (T_ * S_ / 4);
  const int s4  = rem % (S_ / 4);
  const float4 st4 = *(const float4*)&muStat[(size_t)b * T_ * S_ + 4 * s4];
  float4 r = ((const float4*)al)[gid];
  float4 a;
  a.x = __expf(r.x - st4.x);
  a.y = __expf(r.y - st4.y);
  a.z = __expf(r.z - st4.z);
  a.w = __expf(r.w - st4.w);
  ((float4*)al)[gid] = a;
}

// ---------------- DP: redundant-compute quad wave, barrier-paced ---------
// 4 waves (1/SIMD) ALL compute the identical recurrence in registers
// (blocked: lane l owns s=8l..8l+7, ONE shfl/step). Cooperation only on:
// staging (wave r DMAs row 4g+9+r per superstep into 16-slot al/mask LDS
// rings, 8+ rows ahead), output (wave r stores mu row t and pi row t+1 on
// its turn t%4==(r+1)%4 -> 6 stores/wave/superstep), and one RAW s_barrier
// per 4-step superstep. Counted vmcnt(16) once per superstep retires the
// previous superstep's DMA without ever waiting on stores. Whole DP runs in
// base-2 space (n = mu*log2e, exact isomorphism; v_exp/v_log are base-2).
__global__ __launch_bounds__(256, 1)
void dp_quad(const float* __restrict__ Al, const float* __restrict__ Mk,
             float* __restrict__ muOut, float* __restrict__ piOut)
{
  __shared__ float ar[16 * S_];   // al ring, 25.6 KB
  __shared__ float kr[16 * S_];   // mask ring, 25.6 KB
  const int b = blockIdx.x;
  const int r = threadIdx.x >> 6;     // wave 0..3
  const int l = threadIdx.x & 63;
  const int s0raw = l * 8;
  const bool act = (s0raw < S_);      // lanes 0..49
  const int c0 = act ? s0raw : (S_ - 8);

  const float* alb = Al + (size_t)b * T_ * S_;
  const float* mkb = Mk + (size_t)b * T_ * S_;
  float* mub = muOut + (size_t)b * T_ * S_;
  float* pib = piOut + (size_t)b * T_ * S_ * 2;

  constexpr float C2   = 1.44269504f;     // log2(e)
  constexpr float LN2  = 0.693147181f;
  constexpr float NEGN = -1.44269504e9f;  // -1e9 * log2(e)

  float n[8], cur[8];
  float4 pa0, pa1, pk0, pk1;

#define DMA(ring, gbase, row)                                               \
  { const char* s_ = (const char*)((gbase) + (size_t)(row) * S_);           \
    char* d_ = (char*)(ring) + (((row) & 15) * 1600);                       \
    __builtin_amdgcn_global_load_lds(                                       \
      (const __attribute__((address_space(1))) void*)(s_ + l * 16),         \
      (__attribute__((address_space(3))) void*)(d_ + l * 16), 16, 0, 0);    \
    if (l < 36)                                                             \
      __builtin_amdgcn_global_load_lds(                                     \
        (const __attribute__((address_space(1))) void*)(s_ + 1024 + l*16),  \
        (__attribute__((address_space(3))) void*)(d_ + 1024 + l*16), 16, 0, 0); }

#define RDRING(row)                                                         \
  { const float* qa = ar + (((row) & 15) * S_) + c0;                        \
    const float* qk = kr + (((row) & 15) * S_) + c0;                        \
    pa0 = *(const float4*)qa; pa1 = *(const float4*)(qa + 4);               \
    pk0 = *(const float4*)qk; pk1 = *(const float4*)(qk + 4); }

#define MKCUR()                                                             \
  { cur[0] = pa0.x * pk0.x * C2; cur[1] = pa0.y * pk0.y * C2;               \
    cur[2] = pa0.z * pk0.z * C2; cur[3] = pa0.w * pk0.w * C2;               \
    cur[4] = pa1.x * pk1.x * C2; cur[5] = pa1.y * pk1.y * C2;               \
    cur[6] = pa1.z * pk1.z * C2; cur[7] = pa1.w * pk1.w * C2; }

#define CELLS()                                                             \
  { float sh = __shfl_up(n[7], 1);                                          \
    if (l == 0) sh = NEGN;                                                  \
    _Pragma("unroll")                                                       \
    for (int j = 7; j >= 0; j--) {                                          \
      float prev = n[j];                                                    \
      float sft  = (j == 0) ? sh : n[j - 1];                                \
      float d    = prev - sft;                                              \
      float e, lg;                                                          \
      asm("v_exp_f32 %0, %1" : "=v"(e) : "v"(-fabsf(d)));                   \
      asm("v_log_f32 %0, %1" : "=v"(lg) : "v"(1.f + e));                    \
      n[j] = cur[j] + fmaxf(prev, sft) + lg;                                \
    } }

#define STOREMU(t)                                                          \
  if (act) {                                                                \
    float* mw = mub + (size_t)(t) * S_ + c0;                                \
    *(float4*)mw       = make_float4(n[0]*LN2, n[1]*LN2, n[2]*LN2, n[3]*LN2); \
    *(float4*)(mw + 4) = make_float4(n[4]*LN2, n[5]*LN2, n[6]*LN2, n[7]*LN2); }

#define STOREPI(trow)                                                       \
  { float sh2 = __shfl_up(n[7], 1);                                         \
    if (l == 0) sh2 = NEGN;                                                 \
    float o[16];                                                            \
    _Pragma("unroll")                                                       \
    for (int j = 0; j < 8; j++) {                                           \
      float sft = (j == 0) ? sh2 : n[j - 1];                                \
      float d = n[j] - sft;                                                 \
      float e, rc;                                                          \
      asm("v_exp_f32 %0, %1" : "=v"(e) : "v"(-fabsf(d)));                   \
      float q = 1.f + e;                                                    \
      asm("v_rcp_f32 %0, %1" : "=v"(rc) : "v"(q));                          \
      float p0 = (d >= 0.f) ? rc : 1.f - rc;                                \
      o[2*j] = p0; o[2*j+1] = 1.f - p0;                                     \
    }                                                                       \
    if (act) {                                                              \
      float* pw = pib + (size_t)(trow) * (2 * S_) + 2 * c0;                 \
      *(float4*)&pw[0]  = make_float4(o[0],  o[1],  o[2],  o[3]);           \
      *(float4*)&pw[4]  = make_float4(o[4],  o[5],  o[6],  o[7]);           \
      *(float4*)&pw[8]  = make_float4(o[8],  o[9],  o[10], o[11]);          \
      *(float4*)&pw[12] = make_float4(o[12], o[13], o[14], o[15]);          \
    } }

#define STEP(t, turnflag)                                                   \
  { RDRING((t) + 1)                                                         \
    CELLS()                                                                 \
    if (turnflag) { STOREMU(t) STOREPI((t) + 1) }                           \
    MKCUR() }

  // ---- prologue: DMA rows 0..8, base case, stores for rows 0/pi0/pi1 ----
  DMA(ar, alb, r)     DMA(kr, mkb, r)
  DMA(ar, alb, 4 + r) DMA(kr, mkb, 4 + r)
  if (r == 0) { DMA(ar, alb, 8) DMA(kr, mkb, 8) }
  asm volatile("s_waitcnt vmcnt(0)" ::: "memory");
  __syncthreads();

  RDRING(0) MKCUR()
#pragma unroll
  for (int j = 0; j < 8; j++)
    n[j] = cur[j] + ((c0 + j == 0) ? 0.f : NEGN);
  if (r == 0) { STOREMU(0) }
  if (r == 1 && act) {
    float* p0_ = pib + 2 * c0;
#pragma unroll
    for (int q = 0; q < 4; q++)
      *(float4*)&p0_[4 * q] = make_float4(1.f, 0.f, 1.f, 0.f);
  }
  if (r == 2) { STOREPI(1) }
  RDRING(1) MKCUR()                  // cur = row 1

  // ---- main: supersteps g=0..498 (steps 4g+1 .. 4g+4) ----
  for (int g = 0; g < 499; ++g) {
    __builtin_amdgcn_s_barrier();
    const int dr = 4 * g + 9 + r;
    if (dr < T_) { DMA(ar, alb, dr) DMA(kr, mkb, dr) }
    const int tb = 4 * g + 1;
    STEP(tb + 0, (r == 0))
    STEP(tb + 1, (r == 1))
    STEP(tb + 2, (r == 2))
    STEP(tb + 3, (r == 3))
    if (g >= 495) { asm volatile("s_waitcnt vmcnt(0)"  ::: "memory"); }
    else          { asm volatile("s_waitcnt vmcnt(16)" ::: "memory"); }
  }

  // ---- final superstep: steps 1997, 1998, 1999 ----
  __builtin_amdgcn_s_barrier();
  STEP(1997, (r == 0))
  STEP(1998, (r == 1))
  {               // t = 1999: no prefetch, no pi row 2000
    CELLS()
    if (r == 2) { STOREMU(1999) }
  }

#undef DMA
#undef RDRING
#undef MKCUR
#undef CELLS
#undef STOREMU
#undef STOREPI
#undef STEP
}

// -------------------------------------------------------------------------
extern "C" void kernel_launch(void* const* d_in, const int* in_sizes, int n_in,
                              void* d_out, int out_size, void* d_ws, size_t ws_size,
                              hipStream_t stream)
{
  (void)in_sizes; (void)n_in; (void)out_size; (void)d_ws; (void)ws_size;
  const float* x   = (const float*)d_in[0];
  const float* enc = (const float*)d_in[1];
  const float* msk = (const float*)d_in[2];
  const float* w1  = (const float*)d_in[3];
  const float* b1  = (const float*)d_in[4];
  const float* w2  = (const float*)d_in[5];
  const float* b2  = (const float*)d_in[6];
  const float* w3  = (const float*)d_in[7];
  const float* b3  = (const float*)d_in[8];

  float* out = (float*)d_out;
  float* mu  = out;                       // [B,T,S]
  float* pi  = out + NMU;                 // [B,T,S,2]
  float* al  = out + NMU + NPI;           // [B,T,S]
  float* wsp = out + NMU + NPI + NMU;     // [B,T,H] fp32

  // conv scratch inside pi region (consumed before dp_quad writes pi)
  _Float16*  h1  = (_Float16*)(pi + 26000000);       // 16.384M halves
  _Float16*  h2  = (_Float16*)(pi + 35000000);       // 16.384M halves
  _Float16*  wc1 = (_Float16*)(pi + 44000000);
  _Float16*  wc2 = (_Float16*)(pi + 44100000);
  _Float16*  wc3 = (_Float16*)(pi + 44300000);

  hipLaunchKernelGGL(wprep, dim3((256*5*96 +255)/256), dim3(256), 0, stream, w1, wc1, C0_, 96);
  hipLaunchKernelGGL(wprep, dim3((256*5*256+255)/256), dim3(256), 0, stream, w2, wc2, H_, 256);
  hipLaunchKernelGGL(wprep, dim3((256*5*256+255)/256), dim3(256), 0, stream, w3, wc3, H_, 256);

  dim3 cgrid((T_ + 63) / 64, B_);
  hipLaunchKernelGGL((conv_mfma<C0_,  96, true,  false>), cgrid, dim3(256), 0, stream,
                     (const void*)x,  wc1, b1, (void*)h1);
  hipLaunchKernelGGL((conv_mfma<H_,  256, false, false>), cgrid, dim3(256), 0, stream,
                     (const void*)h1, wc2, b2, (void*)h2);
  hipLaunchKernelGGL((conv_mfma<H_,  256, false, true >), cgrid, dim3(256), 0, stream,
                     (const void*)h2, wc3, b3, (void*)wsp);

  hipLaunchKernelGGL(einsum_ts, dim3((T_ + 127) / 128, (S_ + 63) / 64, B_), dim3(256),
                     0, stream, wsp, enc, al);
  hipLaunchKernelGGL(softmax_stats, dim3((S_ + 63) / 64, B_), dim3(256), 0, stream, al, mu);
  hipLaunchKernelGGL(norm_kernel, dim3(NMU / 4 / 256), dim3(256), 0, stream, al, mu);
  hipLaunchKernelGGL(dp_quad, dim3(B_), dim3(256), 0, stream, al, msk, mu, pi);
}

// Round 15
// 1277.300 us; speedup vs baseline: 2.1189x; 1.0043x over previous
//
#include <hip/hip_runtime.h>
#include <hip/hip_bf16.h>

#define B_ 32
#define T_ 2000
#define S_ 400
#define C0_ 80
#define H_ 256

static constexpr float NEGV = -1e9f;
static constexpr int NMU  = B_ * T_ * S_;       // 25,600,000
static constexpr int NPI  = 2 * NMU;            // 51,200,000

typedef _Float16 f16x8 __attribute__((ext_vector_type(8)));
typedef float    f32x4 __attribute__((ext_vector_type(4)));

// ---------------- weight repack: wcat[co][k*CPAD+ci] = w[k][ci][co] ------
__global__ __launch_bounds__(256)
void wprep(const float* __restrict__ w, _Float16* __restrict__ wcat,
           int CIN, int CPAD)
{
  const int tot = 256 * 5 * CPAD;
  int idx = blockIdx.x * 256 + threadIdx.x;
  if (idx >= tot) return;
  int co  = idx / (5 * CPAD);
  int rem = idx - co * (5 * CPAD);
  int k   = rem / CPAD;
  int ci  = rem - k * CPAD;
  float v = (ci < CIN) ? w[((size_t)k * CIN + ci) * H_ + co] : 0.f;
  wcat[idx] = (_Float16)v;
}

// ---------------- conv1d (K=5, SAME) + bias + tanh via f16 MFMA ----------
template<int CIN, int CPAD, bool INF32, bool OUTF32>
__global__ __launch_bounds__(256)
void conv_mfma(const void* __restrict__ xin, const _Float16* __restrict__ wcat,
               const float* __restrict__ bias, void* __restrict__ yout)
{
  constexpr int KK  = 5 * CPAD;      // 480 / 1280
  constexpr int NS  = KK / 32;       // 15 / 40
  constexpr int STR = CPAD + 8;      // LDS row stride
  __shared__ _Float16 xs[68 * STR];
  const int b   = blockIdx.y;
  const int t0  = blockIdx.x * 64;
  const int tid = threadIdx.x;
  const int w   = tid >> 6;
  const int l   = tid & 63;

  if constexpr (INF32) {
    const float* xb = (const float*)xin + (size_t)b * T_ * CIN;
    constexpr int NG = CPAD / 4;
    for (int idx = tid; idx < 68 * NG; idx += 256) {
      int j = idx / NG, g = idx - j * NG;
      int t = t0 - 2 + j;
      int c = g * 4;
      float4 v = make_float4(0.f, 0.f, 0.f, 0.f);
      if (t >= 0 && t < T_ && c < CIN) v = *(const float4*)&xb[(size_t)t * CIN + c];
      _Float16* d = &xs[j * STR + c];
      d[0] = (_Float16)v.x; d[1] = (_Float16)v.y;
      d[2] = (_Float16)v.z; d[3] = (_Float16)v.w;
    }
  } else {
    const _Float16* xb = (const _Float16*)xin + (size_t)b * T_ * CIN;
    constexpr int NG = CPAD / 8;
    for (int idx = tid; idx < 68 * NG; idx += 256) {
      int j = idx / NG, g = idx - j * NG;
      int t = t0 - 2 + j;
      f16x8 v = {(_Float16)0,(_Float16)0,(_Float16)0,(_Float16)0,
                 (_Float16)0,(_Float16)0,(_Float16)0,(_Float16)0};
      if (t >= 0 && t < T_) v = *(const f16x8*)&xb[(size_t)t * CIN + g * 8];
      *(f16x8*)&xs[j * STR + g * 8] = v;
    }
  }
  __syncthreads();

  const int lr = l & 15;
  const int lk = (l >> 4) * 8;

  f32x4 acc[4][4];
  const f32x4 zz = {0.f, 0.f, 0.f, 0.f};
#pragma unroll
  for (int i = 0; i < 4; i++)
#pragma unroll
    for (int j = 0; j < 4; j++) acc[i][j] = zz;

  const _Float16* wbase = wcat + (size_t)(w * 64 + lr) * KK + lk;

  for (int kk = 0; kk < NS; kk++) {
    const int p  = kk * 32;
    const int k  = p / CPAD;
    const int ci = p - k * CPAD;
    f16x8 a0 = *(const f16x8*)&xs[( 0 + lr + k) * STR + ci + lk];
    f16x8 a1 = *(const f16x8*)&xs[(16 + lr + k) * STR + ci + lk];
    f16x8 a2 = *(const f16x8*)&xs[(32 + lr + k) * STR + ci + lk];
    f16x8 a3 = *(const f16x8*)&xs[(48 + lr + k) * STR + ci + lk];
    f16x8 w0 = *(const f16x8*)&wbase[(size_t)( 0) * KK + p];
    f16x8 w1 = *(const f16x8*)&wbase[(size_t)(16) * KK + p];
    f16x8 w2 = *(const f16x8*)&wbase[(size_t)(32) * KK + p];
    f16x8 w3 = *(const f16x8*)&wbase[(size_t)(48) * KK + p];
    acc[0][0] = __builtin_amdgcn_mfma_f32_16x16x32_f16(a0, w0, acc[0][0], 0, 0, 0);
    acc[0][1] = __builtin_amdgcn_mfma_f32_16x16x32_f16(a0, w1, acc[0][1], 0, 0, 0);
    acc[0][2] = __builtin_amdgcn_mfma_f32_16x16x32_f16(a0, w2, acc[0][2], 0, 0, 0);
    acc[0][3] = __builtin_amdgcn_mfma_f32_16x16x32_f16(a0, w3, acc[0][3], 0, 0, 0);
    acc[1][0] = __builtin_amdgcn_mfma_f32_16x16x32_f16(a1, w0, acc[1][0], 0, 0, 0);
    acc[1][1] = __builtin_amdgcn_mfma_f32_16x16x32_f16(a1, w1, acc[1][1], 0, 0, 0);
    acc[1][2] = __builtin_amdgcn_mfma_f32_16x16x32_f16(a1, w2, acc[1][2], 0, 0, 0);
    acc[1][3] = __builtin_amdgcn_mfma_f32_16x16x32_f16(a1, w3, acc[1][3], 0, 0, 0);
    acc[2][0] = __builtin_amdgcn_mfma_f32_16x16x32_f16(a2, w0, acc[2][0], 0, 0, 0);
    acc[2][1] = __builtin_amdgcn_mfma_f32_16x16x32_f16(a2, w1, acc[2][1], 0, 0, 0);
    acc[2][2] = __builtin_amdgcn_mfma_f32_16x16x32_f16(a2, w2, acc[2][2], 0, 0, 0);
    acc[2][3] = __builtin_amdgcn_mfma_f32_16x16x32_f16(a2, w3, acc[2][3], 0, 0, 0);
    acc[3][0] = __builtin_amdgcn_mfma_f32_16x16x32_f16(a3, w0, acc[3][0], 0, 0, 0);
    acc[3][1] = __builtin_amdgcn_mfma_f32_16x16x32_f16(a3, w1, acc[3][1], 0, 0, 0);
    acc[3][2] = __builtin_amdgcn_mfma_f32_16x16x32_f16(a3, w2, acc[3][2], 0, 0, 0);
    acc[3][3] = __builtin_amdgcn_mfma_f32_16x16x32_f16(a3, w3, acc[3][3], 0, 0, 0);
  }

#pragma unroll
  for (int ct = 0; ct < 4; ct++) {
    const int co = w * 64 + ct * 16 + lr;
    const float bv = bias[co];
#pragma unroll
    for (int tt = 0; tt < 4; tt++) {
#pragma unroll
      for (int r = 0; r < 4; r++) {
        const int t = t0 + tt * 16 + (l >> 4) * 4 + r;
        if (t < T_) {
          float v = tanhf(acc[tt][ct][r] + bv);
          if constexpr (OUTF32)
            ((float*)yout)[((size_t)b * T_ + t) * H_ + co] = v;
          else
            ((_Float16*)yout)[((size_t)b * T_ + t) * H_ + co] = (_Float16)v;
        }
      }
    }
  }
}

// ---------------- W[b,t,s] = sum_h Wspec[b,t,h] * src_enc[b,s,h] --------
__global__ __launch_bounds__(256)
void einsum_ts(const float* __restrict__ A, const float* __restrict__ E,
               float* __restrict__ Wg)
{
  constexpr int GT = 128, GS = 64, KC = 16;
  __shared__ float As[KC][GT + 4];
  __shared__ float Bs[KC][GS + 4];
  const int b   = blockIdx.z;
  const int t0  = blockIdx.x * GT;
  const int s0  = blockIdx.y * GS;
  const int tid = threadIdx.x;
  const int tx  = tid & 15;
  const int ty  = tid >> 4;
  float4 acc[8];
#pragma unroll
  for (int i = 0; i < 8; i++) acc[i] = make_float4(0.f, 0.f, 0.f, 0.f);
  const float* Ab = A + (size_t)b * T_ * H_;
  const float* Eb = E + (size_t)b * S_ * H_;
  for (int kc = 0; kc < H_; kc += KC) {
#pragma unroll
    for (int r = 0; r < 2; r++) {
      int f4  = tid + 256 * r;
      int row = f4 >> 2;
      int c4  = f4 & 3;
      int t   = t0 + row;
      float4 v = make_float4(0, 0, 0, 0);
      if (t < T_) v = *(const float4*)&Ab[(size_t)t * H_ + kc + c4 * 4];
      As[c4*4+0][row] = v.x; As[c4*4+1][row] = v.y;
      As[c4*4+2][row] = v.z; As[c4*4+3][row] = v.w;
    }
    {
      int row = tid >> 2;
      int c4  = tid & 3;
      int s   = s0 + row;
      float4 v = make_float4(0, 0, 0, 0);
      if (s < S_) v = *(const float4*)&Eb[(size_t)s * H_ + kc + c4 * 4];
      Bs[c4*4+0][row] = v.x; Bs[c4*4+1][row] = v.y;
      Bs[c4*4+2][row] = v.z; Bs[c4*4+3][row] = v.w;
    }
    __syncthreads();
#pragma unroll
    for (int kk = 0; kk < KC; kk++) {
      float4 a0 = *(const float4*)&As[kk][ty * 8];
      float4 a1 = *(const float4*)&As[kk][ty * 8 + 4];
      float4 bb = *(const float4*)&Bs[kk][tx * 4];
      float av[8] = {a0.x, a0.y, a0.z, a0.w, a1.x, a1.y, a1.z, a1.w};
#pragma unroll
      for (int i = 0; i < 8; i++) {
        acc[i].x = fmaf(av[i], bb.x, acc[i].x);
        acc[i].y = fmaf(av[i], bb.y, acc[i].y);
        acc[i].z = fmaf(av[i], bb.z, acc[i].z);
        acc[i].w = fmaf(av[i], bb.w, acc[i].w);
      }
    }
    __syncthreads();
  }
  float* Wb = Wg + (size_t)b * T_ * S_;
  const int s = s0 + tx * 4;
#pragma unroll
  for (int i = 0; i < 8; i++) {
    int t = t0 + ty * 8 + i;
    if (t < T_ && s < S_) *(float4*)&Wb[(size_t)t * S_ + s] = acc[i];
  }
}

// ---------------- per-(b,s) column softmax stats over T ------------------
// Writes M + ln(L) into stats[b][s] (stats buffer lives in the pi tail).
__global__ __launch_bounds__(256)
void softmax_stats(const float* __restrict__ Wg, float* __restrict__ statsOut)
{
  const int b  = blockIdx.y;
  const int tx = threadIdx.x & 63;
  const int ty = threadIdx.x >> 6;            // 0..3
  const int s  = blockIdx.x * 64 + tx;
  const bool act = (s < S_);
  float m = -1e30f, l = 0.f;
  if (act) {
    const float* col = Wg + (size_t)b * T_ * S_ + s;
#pragma unroll 4
    for (int t = ty; t < T_; t += 4) {
      float v  = col[(size_t)t * S_];
      float nm = fmaxf(m, v);
      l = l * __expf(m - nm) + __expf(v - nm);
      m = nm;
    }
  }
  __shared__ float rm[4][64], rl[4][64];
  rm[ty][tx] = m; rl[ty][tx] = l;
  __syncthreads();
  if (ty == 0 && act) {
    float M = rm[0][tx];
#pragma unroll
    for (int q = 1; q < 4; q++) M = fmaxf(M, rm[q][tx]);
    float L = 0.f;
#pragma unroll
    for (int q = 0; q < 4; q++) L += rl[q][tx] * __expf(rm[q][tx] - M);
    statsOut[(size_t)b * S_ + s] = M + __logf(L);
  }
}

// ---------------- normalize: al = exp(raw-stat); wdp = al*mask*log2e ----
// wdp is written into the MU region (aliased; dp_skew DMA-reads each row
// several phases before overwriting it with mu).
__global__ __launch_bounds__(256)
void norm_kernel(float* __restrict__ al, const float* __restrict__ Mk,
                 const float* __restrict__ stats, float* __restrict__ wdp)
{
  constexpr float C2 = 1.44269504f;
  const int gid = blockIdx.x * 256 + threadIdx.x;
  if (gid >= NMU / 4) return;
  const int b   = gid / (T_ * S_ / 4);
  const int rem = gid - b * (T_ * S_ / 4);
  const int s4  = rem % (S_ / 4);
  const float4 st4 = *(const float4*)&stats[(size_t)b * S_ + 4 * s4];
  float4 r = ((const float4*)al)[gid];
  float4 k = ((const float4*)Mk)[gid];
  float4 a;
  a.x = __expf(r.x - st4.x);
  a.y = __expf(r.y - st4.y);
  a.z = __expf(r.z - st4.z);
  a.w = __expf(r.w - st4.w);
  ((float4*)al)[gid] = a;
  ((float4*)wdp)[gid] = make_float4(a.x * k.x * C2, a.y * k.y * C2,
                                    a.z * k.z * C2, a.w * k.w * C2);
}

// ---------------- DP: skewed 4-wave pipeline, barrier-paced --------------
// Wave w owns cols [100w,100w+100) (2 cells/lane, lanes 0..49) and runs
// block j (rows 4j+1..4j+4) at phase p=j+w+1 (base case row 0 at p=w).
// Cross-wave s-1 boundary flows through bnd[16][4] (written phase p, read
// phase p+1 -> race-free by the per-phase s_barrier; lgkmcnt(0) before it).
// One wdp ring (28 rows, DMA'd 8+w rows ahead via registerless
// global_load_lds). vmcnt(10) at phase start retires 2-phase-old DMAs
// without waiting on the ~8 stores of the previous phase (FIFO count).
// All math in base-2 space (wdp pre-scaled by log2e; mu scaled back by ln2).
// pi row t is computed from the same d,e as step t's recurrence (fused).
__global__ __launch_bounds__(256, 1)
void dp_skew(const float* Wdp, float* muOut, float* piOut)
{
  __shared__ float ring[28 * S_];     // 44.8 KB
  __shared__ float bnd[16][4];
  const int b = blockIdx.x;
  const int w = threadIdx.x >> 6;
  const int l = threadIdx.x & 63;
  const int lc = (l < 50) ? l : 49;
  const bool act = (l < 50);
  const int sc = 100 * w + 2 * lc;

  const float* wb  = Wdp   + (size_t)b * T_ * S_;
  float*       mub = muOut + (size_t)b * T_ * S_;
  float*       pib = piOut + (size_t)(2 * b) * T_ * S_;

  constexpr float LN2  = 0.693147181f;
  constexpr float NEGN = -1.44269504e9f;   // -1e9 * log2(e)

#define DMA(row, slot)                                                      \
  { const char* s_ = (const char*)(wb + (size_t)(row) * S_);                \
    char* d_ = (char*)ring + ((slot) * 1600);                               \
    __builtin_amdgcn_global_load_lds(                                       \
      (const __attribute__((address_space(1))) void*)(s_ + l * 16),         \
      (__attribute__((address_space(3))) void*)(d_ + l * 16), 16, 0, 0);    \
    if (l < 36)                                                             \
      __builtin_amdgcn_global_load_lds(                                     \
        (const __attribute__((address_space(1))) void*)(s_ + 1024 + l*16),  \
        (__attribute__((address_space(3))) void*)(d_ + 1024 + l*16), 16, 0, 0); }

  // prologue: rows 0..7 (2 per wave)
  DMA(w, w) DMA(4 + w, 4 + w)
  asm volatile("s_waitcnt vmcnt(0)" ::: "memory");
  __syncthreads();

  float n0 = 0.f, n1 = 0.f;
  int ds = 8 + w;                  // ring slot for DMA row 4p+8+w
  int rs = 1;                      // ring slot of row 4j+1 for this wave's block

  for (int p = 0; p <= 503; ++p) {
    __builtin_amdgcn_s_barrier();
    asm volatile("s_waitcnt vmcnt(10)" ::: "memory");
    {
      const int dr = 4 * p + 8 + w;
      if (dr < T_) DMA(dr, ds)
      ds += 4; if (ds >= 28) ds -= 28;
    }
    if (p == w) {
      // base case: row 0
      float2 cur = *(const float2*)&ring[sc];          // slot 0
      n0 = cur.x + ((sc == 0) ? 0.f : NEGN);
      n1 = cur.y + NEGN;                               // sc+1 >= 1 always
      if (act) {
        *(float2*)&mub[sc] = make_float2(n0 * LN2, n1 * LN2);
        *(float4*)&pib[2 * sc] = make_float4(1.f, 0.f, 1.f, 0.f);
      }
      if (l == 49) bnd[0][w] = n1;
      asm volatile("s_waitcnt lgkmcnt(0)" ::: "memory");
    } else if (p > w && p - w <= 500) {
      const int tb = 4 * (p - w - 1) + 1;
#pragma unroll
      for (int k = 0; k < 4; ++k) {
        const int t = tb + k;
        if (t < T_) {                                  // wave-uniform
          int sk = rs + k; if (sk >= 28) sk -= 28;
          float2 cur = *(const float2*)&ring[sk * S_ + sc];
          float bp = bnd[(t - 1) & 15][(w > 0) ? (w - 1) : 0];
          float sh = __shfl_up(n1, 1);
          float sft0 = (l == 0) ? ((w == 0) ? NEGN : bp) : sh;
          // cell 0
          float d0 = n0 - sft0;
          float e0; asm("v_exp_f32 %0, %1" : "=v"(e0) : "v"(-fabsf(d0)));
          float q0 = 1.f + e0;
          float lg0; asm("v_log_f32 %0, %1" : "=v"(lg0) : "v"(q0));
          float rc0; asm("v_rcp_f32 %0, %1" : "=v"(rc0) : "v"(q0));
          float p00 = (d0 >= 0.f) ? rc0 : 1.f - rc0;
          float nn0 = cur.x + fmaxf(n0, sft0) + lg0;
          // cell 1 (neighbor is same-lane cell 0, previous row)
          float d1 = n1 - n0;
          float e1; asm("v_exp_f32 %0, %1" : "=v"(e1) : "v"(-fabsf(d1)));
          float q1 = 1.f + e1;
          float lg1; asm("v_log_f32 %0, %1" : "=v"(lg1) : "v"(q1));
          float rc1; asm("v_rcp_f32 %0, %1" : "=v"(rc1) : "v"(q1));
          float p01 = (d1 >= 0.f) ? rc1 : 1.f - rc1;
          float nn1 = cur.y + fmaxf(n1, n0) + lg1;
          if (act) {
            *(float2*)&mub[(size_t)t * S_ + sc] = make_float2(nn0 * LN2, nn1 * LN2);
            *(float4*)&pib[(size_t)t * (2 * S_) + 2 * sc] =
                make_float4(p00, 1.f - p00, p01, 1.f - p01);
          }
          n0 = nn0; n1 = nn1;
          if (l == 49) bnd[t & 15][w] = n1;
        }
      }
      rs += 4; if (rs >= 28) rs -= 28;
      asm volatile("s_waitcnt lgkmcnt(0)" ::: "memory");
    }
  }
#undef DMA
}

// -------------------------------------------------------------------------
extern "C" void kernel_launch(void* const* d_in, const int* in_sizes, int n_in,
                              void* d_out, int out_size, void* d_ws, size_t ws_size,
                              hipStream_t stream)
{
  (void)in_sizes; (void)n_in; (void)out_size; (void)d_ws; (void)ws_size;
  const float* x   = (const float*)d_in[0];
  const float* enc = (const float*)d_in[1];
  const float* msk = (const float*)d_in[2];
  const float* w1  = (const float*)d_in[3];
  const float* b1  = (const float*)d_in[4];
  const float* w2  = (const float*)d_in[5];
  const float* b2  = (const float*)d_in[6];
  const float* w3  = (const float*)d_in[7];
  const float* b3  = (const float*)d_in[8];

  float* out = (float*)d_out;
  float* mu  = out;                       // [B,T,S]  (holds wdp before dp)
  float* pi  = out + NMU;                 // [B,T,S,2]
  float* al  = out + NMU + NPI;           // [B,T,S]
  float* wsp = out + NMU + NPI + NMU;     // [B,T,H] fp32

  // scratch inside pi region (consumed before dp_skew writes pi)
  _Float16*  h1  = (_Float16*)(pi + 26000000);       // 16.384M halves
  _Float16*  h2  = (_Float16*)(pi + 35000000);       // 16.384M halves
  _Float16*  wc1 = (_Float16*)(pi + 44000000);
  _Float16*  wc2 = (_Float16*)(pi + 44100000);
  _Float16*  wc3 = (_Float16*)(pi + 44300000);
  float*     pistats = pi + NPI - 13056;             // [B,S] softmax stats

  hipLaunchKernelGGL(wprep, dim3((256*5*96 +255)/256), dim3(256), 0, stream, w1, wc1, C0_, 96);
  hipLaunchKernelGGL(wprep, dim3((256*5*256+255)/256), dim3(256), 0, stream, w2, wc2, H_, 256);
  hipLaunchKernelGGL(wprep, dim3((256*5*256+255)/256), dim3(256), 0, stream, w3, wc3, H_, 256);

  dim3 cgrid((T_ + 63) / 64, B_);
  hipLaunchKernelGGL((conv_mfma<C0_,  96, true,  false>), cgrid, dim3(256), 0, stream,
                     (const void*)x,  wc1, b1, (void*)h1);
  hipLaunchKernelGGL((conv_mfma<H_,  256, false, false>), cgrid, dim3(256), 0, stream,
                     (const void*)h1, wc2, b2, (void*)h2);
  hipLaunchKernelGGL((conv_mfma<H_,  256, false, true >), cgrid, dim3(256), 0, stream,
                     (const void*)h2, wc3, b3, (void*)wsp);

  hipLaunchKernelGGL(einsum_ts, dim3((T_ + 127) / 128, (S_ + 63) / 64, B_), dim3(256),
                     0, stream, wsp, enc, al);
  hipLaunchKernelGGL(softmax_stats, dim3((S_ + 63) / 64, B_), dim3(256), 0, stream, al, pistats);
  hipLaunchKernelGGL(norm_kernel, dim3(NMU / 4 / 256), dim3(256), 0, stream, al, msk, pistats, mu);
  hipLaunchKernelGGL(dp_skew, dim3(B_), dim3(256), 0, stream, mu, mu, pi);
}

// Round 16
// 1191.804 us; speedup vs baseline: 2.2709x; 1.0717x over previous
//
#include <hip/hip_runtime.h>
#include <hip/hip_bf16.h>

#define B_ 32
#define T_ 2000
#define S_ 400
#define C0_ 80
#define H_ 256

static constexpr float NEGV = -1e9f;
static constexpr int NMU  = B_ * T_ * S_;       // 25,600,000
static constexpr int NPI  = 2 * NMU;            // 51,200,000

typedef _Float16 f16x8 __attribute__((ext_vector_type(8)));
typedef float    f32x4 __attribute__((ext_vector_type(4)));

// ---------------- weight repack: wcat[co][k*CPAD+ci] = w[k][ci][co] ------
__global__ __launch_bounds__(256)
void wprep(const float* __restrict__ w, _Float16* __restrict__ wcat,
           int CIN, int CPAD)
{
  const int tot = 256 * 5 * CPAD;
  int idx = blockIdx.x * 256 + threadIdx.x;
  if (idx >= tot) return;
  int co  = idx / (5 * CPAD);
  int rem = idx - co * (5 * CPAD);
  int k   = rem / CPAD;
  int ci  = rem - k * CPAD;
  float v = (ci < CIN) ? w[((size_t)k * CIN + ci) * H_ + co] : 0.f;
  wcat[idx] = (_Float16)v;
}

// ---------------- conv1d (K=5, SAME) + bias + tanh via f16 MFMA ----------
template<int CIN, int CPAD, bool INF32, bool OUTF32>
__global__ __launch_bounds__(256)
void conv_mfma(const void* __restrict__ xin, const _Float16* __restrict__ wcat,
               const float* __restrict__ bias, void* __restrict__ yout)
{
  constexpr int KK  = 5 * CPAD;      // 480 / 1280
  constexpr int NS  = KK / 32;       // 15 / 40
  constexpr int STR = CPAD + 8;      // LDS row stride
  __shared__ _Float16 xs[68 * STR];
  const int b   = blockIdx.y;
  const int t0  = blockIdx.x * 64;
  const int tid = threadIdx.x;
  const int w   = tid >> 6;
  const int l   = tid & 63;

  if constexpr (INF32) {
    const float* xb = (const float*)xin + (size_t)b * T_ * CIN;
    constexpr int NG = CPAD / 4;
    for (int idx = tid; idx < 68 * NG; idx += 256) {
      int j = idx / NG, g = idx - j * NG;
      int t = t0 - 2 + j;
      int c = g * 4;
      float4 v = make_float4(0.f, 0.f, 0.f, 0.f);
      if (t >= 0 && t < T_ && c < CIN) v = *(const float4*)&xb[(size_t)t * CIN + c];
      _Float16* d = &xs[j * STR + c];
      d[0] = (_Float16)v.x; d[1] = (_Float16)v.y;
      d[2] = (_Float16)v.z; d[3] = (_Float16)v.w;
    }
  } else {
    const _Float16* xb = (const _Float16*)xin + (size_t)b * T_ * CIN;
    constexpr int NG = CPAD / 8;
    for (int idx = tid; idx < 68 * NG; idx += 256) {
      int j = idx / NG, g = idx - j * NG;
      int t = t0 - 2 + j;
      f16x8 v = {(_Float16)0,(_Float16)0,(_Float16)0,(_Float16)0,
                 (_Float16)0,(_Float16)0,(_Float16)0,(_Float16)0};
      if (t >= 0 && t < T_) v = *(const f16x8*)&xb[(size_t)t * CIN + g * 8];
      *(f16x8*)&xs[j * STR + g * 8] = v;
    }
  }
  __syncthreads();

  const int lr = l & 15;
  const int lk = (l >> 4) * 8;

  f32x4 acc[4][4];
  const f32x4 zz = {0.f, 0.f, 0.f, 0.f};
#pragma unroll
  for (int i = 0; i < 4; i++)
#pragma unroll
    for (int j = 0; j < 4; j++) acc[i][j] = zz;

  const _Float16* wbase = wcat + (size_t)(w * 64 + lr) * KK + lk;

  for (int kk = 0; kk < NS; kk++) {
    const int p  = kk * 32;
    const int k  = p / CPAD;
    const int ci = p - k * CPAD;
    f16x8 a0 = *(const f16x8*)&xs[( 0 + lr + k) * STR + ci + lk];
    f16x8 a1 = *(const f16x8*)&xs[(16 + lr + k) * STR + ci + lk];
    f16x8 a2 = *(const f16x8*)&xs[(32 + lr + k) * STR + ci + lk];
    f16x8 a3 = *(const f16x8*)&xs[(48 + lr + k) * STR + ci + lk];
    f16x8 w0 = *(const f16x8*)&wbase[(size_t)( 0) * KK + p];
    f16x8 w1 = *(const f16x8*)&wbase[(size_t)(16) * KK + p];
    f16x8 w2 = *(const f16x8*)&wbase[(size_t)(32) * KK + p];
    f16x8 w3 = *(const f16x8*)&wbase[(size_t)(48) * KK + p];
    acc[0][0] = __builtin_amdgcn_mfma_f32_16x16x32_f16(a0, w0, acc[0][0], 0, 0, 0);
    acc[0][1] = __builtin_amdgcn_mfma_f32_16x16x32_f16(a0, w1, acc[0][1], 0, 0, 0);
    acc[0][2] = __builtin_amdgcn_mfma_f32_16x16x32_f16(a0, w2, acc[0][2], 0, 0, 0);
    acc[0][3] = __builtin_amdgcn_mfma_f32_16x16x32_f16(a0, w3, acc[0][3], 0, 0, 0);
    acc[1][0] = __builtin_amdgcn_mfma_f32_16x16x32_f16(a1, w0, acc[1][0], 0, 0, 0);
    acc[1][1] = __builtin_amdgcn_mfma_f32_16x16x32_f16(a1, w1, acc[1][1], 0, 0, 0);
    acc[1][2] = __builtin_amdgcn_mfma_f32_16x16x32_f16(a1, w2, acc[1][2], 0, 0, 0);
    acc[1][3] = __builtin_amdgcn_mfma_f32_16x16x32_f16(a1, w3, acc[1][3], 0, 0, 0);
    acc[2][0] = __builtin_amdgcn_mfma_f32_16x16x32_f16(a2, w0, acc[2][0], 0, 0, 0);
    acc[2][1] = __builtin_amdgcn_mfma_f32_16x16x32_f16(a2, w1, acc[2][1], 0, 0, 0);
    acc[2][2] = __builtin_amdgcn_mfma_f32_16x16x32_f16(a2, w2, acc[2][2], 0, 0, 0);
    acc[2][3] = __builtin_amdgcn_mfma_f32_16x16x32_f16(a2, w3, acc[2][3], 0, 0, 0);
    acc[3][0] = __builtin_amdgcn_mfma_f32_16x16x32_f16(a3, w0, acc[3][0], 0, 0, 0);
    acc[3][1] = __builtin_amdgcn_mfma_f32_16x16x32_f16(a3, w1, acc[3][1], 0, 0, 0);
    acc[3][2] = __builtin_amdgcn_mfma_f32_16x16x32_f16(a3, w2, acc[3][2], 0, 0, 0);
    acc[3][3] = __builtin_amdgcn_mfma_f32_16x16x32_f16(a3, w3, acc[3][3], 0, 0, 0);
  }

#pragma unroll
  for (int ct = 0; ct < 4; ct++) {
    const int co = w * 64 + ct * 16 + lr;
    const float bv = bias[co];
#pragma unroll
    for (int tt = 0; tt < 4; tt++) {
#pragma unroll
      for (int r = 0; r < 4; r++) {
        const int t = t0 + tt * 16 + (l >> 4) * 4 + r;
        if (t < T_) {
          float v = tanhf(acc[tt][ct][r] + bv);
          if constexpr (OUTF32)
            ((float*)yout)[((size_t)b * T_ + t) * H_ + co] = v;
          else
            ((_Float16*)yout)[((size_t)b * T_ + t) * H_ + co] = (_Float16)v;
        }
      }
    }
  }
}

// ---------------- W[b,t,s] = sum_h Wspec[b,t,h] * src_enc[b,s,h] --------
__global__ __launch_bounds__(256)
void einsum_ts(const float* __restrict__ A, const float* __restrict__ E,
               float* __restrict__ Wg)
{
  constexpr int GT = 128, GS = 64, KC = 16;
  __shared__ float As[KC][GT + 4];
  __shared__ float Bs[KC][GS + 4];
  const int b   = blockIdx.z;
  const int t0  = blockIdx.x * GT;
  const int s0  = blockIdx.y * GS;
  const int tid = threadIdx.x;
  const int tx  = tid & 15;
  const int ty  = tid >> 4;
  float4 acc[8];
#pragma unroll
  for (int i = 0; i < 8; i++) acc[i] = make_float4(0.f, 0.f, 0.f, 0.f);
  const float* Ab = A + (size_t)b * T_ * H_;
  const float* Eb = E + (size_t)b * S_ * H_;
  for (int kc = 0; kc < H_; kc += KC) {
#pragma unroll
    for (int r = 0; r < 2; r++) {
      int f4  = tid + 256 * r;
      int row = f4 >> 2;
      int c4  = f4 & 3;
      int t   = t0 + row;
      float4 v = make_float4(0, 0, 0, 0);
      if (t < T_) v = *(const float4*)&Ab[(size_t)t * H_ + kc + c4 * 4];
      As[c4*4+0][row] = v.x; As[c4*4+1][row] = v.y;
      As[c4*4+2][row] = v.z; As[c4*4+3][row] = v.w;
    }
    {
      int row = tid >> 2;
      int c4  = tid & 3;
      int s   = s0 + row;
      float4 v = make_float4(0, 0, 0, 0);
      if (s < S_) v = *(const float4*)&Eb[(size_t)s * H_ + kc + c4 * 4];
      Bs[c4*4+0][row] = v.x; Bs[c4*4+1][row] = v.y;
      Bs[c4*4+2][row] = v.z; Bs[c4*4+3][row] = v.w;
    }
    __syncthreads();
#pragma unroll
    for (int kk = 0; kk < KC; kk++) {
      float4 a0 = *(const float4*)&As[kk][ty * 8];
      float4 a1 = *(const float4*)&As[kk][ty * 8 + 4];
      float4 bb = *(const float4*)&Bs[kk][tx * 4];
      float av[8] = {a0.x, a0.y, a0.z, a0.w, a1.x, a1.y, a1.z, a1.w};
#pragma unroll
      for (int i = 0; i < 8; i++) {
        acc[i].x = fmaf(av[i], bb.x, acc[i].x);
        acc[i].y = fmaf(av[i], bb.y, acc[i].y);
        acc[i].z = fmaf(av[i], bb.z, acc[i].z);
        acc[i].w = fmaf(av[i], bb.w, acc[i].w);
      }
    }
    __syncthreads();
  }
  float* Wb = Wg + (size_t)b * T_ * S_;
  const int s = s0 + tx * 4;
#pragma unroll
  for (int i = 0; i < 8; i++) {
    int t = t0 + ty * 8 + i;
    if (t < T_ && s < S_) *(float4*)&Wb[(size_t)t * S_ + s] = acc[i];
  }
}

// ---------------- per-(b,s) column softmax stats over T ------------------
// Writes M + ln(L) into stats[b][s] (stats buffer lives in the pi tail).
__global__ __launch_bounds__(256)
void softmax_stats(const float* __restrict__ Wg, float* __restrict__ statsOut)
{
  const int b  = blockIdx.y;
  const int tx = threadIdx.x & 63;
  const int ty = threadIdx.x >> 6;            // 0..3
  const int s  = blockIdx.x * 64 + tx;
  const bool act = (s < S_);
  float m = -1e30f, l = 0.f;
  if (act) {
    const float* col = Wg + (size_t)b * T_ * S_ + s;
#pragma unroll 4
    for (int t = ty; t < T_; t += 4) {
      float v  = col[(size_t)t * S_];
      float nm = fmaxf(m, v);
      l = l * __expf(m - nm) + __expf(v - nm);
      m = nm;
    }
  }
  __shared__ float rm[4][64], rl[4][64];
  rm[ty][tx] = m; rl[ty][tx] = l;
  __syncthreads();
  if (ty == 0 && act) {
    float M = rm[0][tx];
#pragma unroll
    for (int q = 1; q < 4; q++) M = fmaxf(M, rm[q][tx]);
    float L = 0.f;
#pragma unroll
    for (int q = 0; q < 4; q++) L += rl[q][tx] * __expf(rm[q][tx] - M);
    statsOut[(size_t)b * S_ + s] = M + __logf(L);
  }
}

// ---------------- normalize: al = exp(raw-stat); wdp = al*mask*log2e ----
// wdp is written into the MU region (aliased; dp reads each row several
// phases before overwriting it with mu).
__global__ __launch_bounds__(256)
void norm_kernel(float* __restrict__ al, const float* __restrict__ Mk,
                 const float* __restrict__ stats, float* __restrict__ wdp)
{
  constexpr float C2 = 1.44269504f;
  const int gid = blockIdx.x * 256 + threadIdx.x;
  if (gid >= NMU / 4) return;
  const int b   = gid / (T_ * S_ / 4);
  const int rem = gid - b * (T_ * S_ / 4);
  const int s4  = rem % (S_ / 4);
  const float4 st4 = *(const float4*)&stats[(size_t)b * S_ + 4 * s4];
  float4 r = ((const float4*)al)[gid];
  float4 k = ((const float4*)Mk)[gid];
  float4 a;
  a.x = __expf(r.x - st4.x);
  a.y = __expf(r.y - st4.y);
  a.z = __expf(r.z - st4.z);
  a.w = __expf(r.w - st4.w);
  ((float4*)al)[gid] = a;
  ((float4*)wdp)[gid] = make_float4(a.x * k.x * C2, a.y * k.y * C2,
                                    a.z * k.z * C2, a.w * k.w * C2);
}

// ---------------- DP: skewed 4-wave pipeline, 8 rows/phase ---------------
// Wave w owns cols [100w,100w+100) (2 cells/lane) and runs block j
// (rows 8j+1..8j+8) at phase p=j+w+1 (base case row 0 at p=w). 254 phases.
// Ring: 64 rows (102.4 KB), DMA'd rows 8p+24+2w(+1) per wave per phase.
// Hoisted reads: 8 ring b64 + 8 bnd b32 issued at phase start (one latency).
// Cross-wave s-1 boundary: bnd[32][4], written phase p, read >= p+1.
// Race-free DMA visibility: vmcnt(56) at phase end (20 vmem ops/phase;
// retires own phase-(p-2) DMAs, never waits on recent stores) BEFORE the
// barrier; consumers read rows staged >= 3 phases back. Base-2 space.
__global__ __launch_bounds__(256, 1)
void dp_skew2(const float* Wdp, float* muOut, float* piOut)
{
  __shared__ float ring[64 * S_];     // 102.4 KB
  __shared__ float bnd[32][4];
  const int b = blockIdx.x;
  const int w = threadIdx.x >> 6;
  const int l = threadIdx.x & 63;
  const int lc = (l < 50) ? l : 49;
  const bool act = (l < 50);
  const int sc = 100 * w + 2 * lc;

  const float* wb  = Wdp   + (size_t)b * T_ * S_;
  float*       mub = muOut + (size_t)b * T_ * S_;
  float*       pib = piOut + (size_t)(2 * b) * T_ * S_;

  constexpr float LN2  = 0.693147181f;
  constexpr float NEGN = -1.44269504e9f;   // -1e9 * log2(e)

#define DMA(row)                                                            \
  { const char* s_ = (const char*)(wb + (size_t)(row) * S_);                \
    char* d_ = (char*)ring + (((row) & 63) * 1600);                         \
    __builtin_amdgcn_global_load_lds(                                       \
      (const __attribute__((address_space(1))) void*)(s_ + l * 16),         \
      (__attribute__((address_space(3))) void*)(d_ + l * 16), 16, 0, 0);    \
    if (l < 36)                                                             \
      __builtin_amdgcn_global_load_lds(                                     \
        (const __attribute__((address_space(1))) void*)(s_ + 1024 + l*16),  \
        (__attribute__((address_space(3))) void*)(d_ + 1024 + l*16), 16, 0, 0); }

  // prologue: rows 0..23 (6 per wave)
#pragma unroll
  for (int i = 0; i < 6; ++i) { const int r0 = 6 * w + i; DMA(r0) }
  asm volatile("s_waitcnt vmcnt(0)" ::: "memory");
  __syncthreads();

  float n0 = NEGN, n1 = NEGN;

  for (int p = 0; p <= 253; ++p) {
    __builtin_amdgcn_s_barrier();
    const int j = p - w - 1;

    // ---- unconditional DMA (rows 8p+24+2w, +1) ----
    {
      const int dr = 8 * p + 24 + 2 * w;
      if (dr < T_) DMA(dr)
      const int dr1 = dr + 1;
      if (dr1 < T_) DMA(dr1)
    }

    if (p == w) {
      // base case: row 0 (ring slot 0, prologue-staged)
      float2 c0v = *(const float2*)&ring[sc];
      n0 = c0v.x + ((sc == 0) ? 0.f : NEGN);
      n1 = c0v.y + NEGN;
      if (act) {
        *(float2*)&mub[sc] = make_float2(n0 * LN2, n1 * LN2);
        *(float4*)&pib[2 * sc] = make_float4(1.f, 0.f, 1.f, 0.f);
      }
      if (l == 49) bnd[0][w] = n1;
    } else if (j >= 0 && j <= 249) {
      const int tb = 8 * j + 1;
      // ---- hoisted independent reads ----
      float2 cur[8];
      float  bq[8];
#pragma unroll
      for (int k = 0; k < 8; ++k) {
        const int t = tb + k;
        cur[k] = (t < T_) ? *(const float2*)&ring[(t & 63) * S_ + sc]
                          : make_float2(0.f, 0.f);
        bq[k] = (w > 0) ? bnd[(t - 1) & 31][w - 1] : NEGN;
      }
      // ---- compute 8 steps ----
      float* mrow = mub + (size_t)tb * S_ + sc;
      float* prow = pib + (size_t)tb * (2 * S_) + 2 * sc;
#pragma unroll
      for (int k = 0; k < 8; ++k) {
        const int t = tb + k;
        if (t < T_) {                                    // wave-uniform
          float sh = __shfl_up(n1, 1);
          float sft0 = (l == 0) ? bq[k] : sh;
          float d0 = n0 - sft0;
          float e0; asm("v_exp_f32 %0, %1" : "=v"(e0) : "v"(-fabsf(d0)));
          float q0 = 1.f + e0;
          float lg0; asm("v_log_f32 %0, %1" : "=v"(lg0) : "v"(q0));
          float rc0; asm("v_rcp_f32 %0, %1" : "=v"(rc0) : "v"(q0));
          float p00 = (d0 >= 0.f) ? rc0 : 1.f - rc0;
          float nn0 = cur[k].x + fmaxf(n0, sft0) + lg0;
          float d1 = n1 - n0;
          float e1; asm("v_exp_f32 %0, %1" : "=v"(e1) : "v"(-fabsf(d1)));
          float q1 = 1.f + e1;
          float lg1; asm("v_log_f32 %0, %1" : "=v"(lg1) : "v"(q1));
          float rc1; asm("v_rcp_f32 %0, %1" : "=v"(rc1) : "v"(q1));
          float p01 = (d1 >= 0.f) ? rc1 : 1.f - rc1;
          float nn1 = cur[k].y + fmaxf(n1, n0) + lg1;
          if (act) {
            *(float2*)mrow = make_float2(nn0 * LN2, nn1 * LN2);
            *(float4*)prow = make_float4(p00, 1.f - p00, p01, 1.f - p01);
          }
          n0 = nn0; n1 = nn1;
          if (l == 49) bnd[t & 31][w] = n1;
        }
        mrow += S_;
        prow += 2 * S_;
      }
    }
    // publish bnd (lgkm) and retire own phase-(p-2) DMAs (vm) pre-barrier
    asm volatile("s_waitcnt lgkmcnt(0)" ::: "memory");
    asm volatile("s_waitcnt vmcnt(56)" ::: "memory");
  }
#undef DMA
}

// -------------------------------------------------------------------------
extern "C" void kernel_launch(void* const* d_in, const int* in_sizes, int n_in,
                              void* d_out, int out_size, void* d_ws, size_t ws_size,
                              hipStream_t stream)
{
  (void)in_sizes; (void)n_in; (void)out_size; (void)d_ws; (void)ws_size;
  const float* x   = (const float*)d_in[0];
  const float* enc = (const float*)d_in[1];
  const float* msk = (const float*)d_in[2];
  const float* w1  = (const float*)d_in[3];
  const float* b1  = (const float*)d_in[4];
  const float* w2  = (const float*)d_in[5];
  const float* b2  = (const float*)d_in[6];
  const float* w3  = (const float*)d_in[7];
  const float* b3  = (const float*)d_in[8];

  float* out = (float*)d_out;
  float* mu  = out;                       // [B,T,S]  (holds wdp before dp)
  float* pi  = out + NMU;                 // [B,T,S,2]
  float* al  = out + NMU + NPI;           // [B,T,S]
  float* wsp = out + NMU + NPI + NMU;     // [B,T,H] fp32

  // scratch inside pi region (consumed before dp_skew2 writes pi)
  _Float16*  h1  = (_Float16*)(pi + 26000000);       // 16.384M halves
  _Float16*  h2  = (_Float16*)(pi + 35000000);       // 16.384M halves
  _Float16*  wc1 = (_Float16*)(pi + 44000000);
  _Float16*  wc2 = (_Float16*)(pi + 44100000);
  _Float16*  wc3 = (_Float16*)(pi + 44300000);
  float*     pistats = pi + NPI - 13056;             // [B,S] softmax stats

  hipLaunchKernelGGL(wprep, dim3((256*5*96 +255)/256), dim3(256), 0, stream, w1, wc1, C0_, 96);
  hipLaunchKernelGGL(wprep, dim3((256*5*256+255)/256), dim3(256), 0, stream, w2, wc2, H_, 256);
  hipLaunchKernelGGL(wprep, dim3((256*5*256+255)/256), dim3(256), 0, stream, w3, wc3, H_, 256);

  dim3 cgrid((T_ + 63) / 64, B_);
  hipLaunchKernelGGL((conv_mfma<C0_,  96, true,  false>), cgrid, dim3(256), 0, stream,
                     (const void*)x,  wc1, b1, (void*)h1);
  hipLaunchKernelGGL((conv_mfma<H_,  256, false, false>), cgrid, dim3(256), 0, stream,
                     (const void*)h1, wc2, b2, (void*)h2);
  hipLaunchKernelGGL((conv_mfma<H_,  256, false, true >), cgrid, dim3(256), 0, stream,
                     (const void*)h2, wc3, b3, (void*)wsp);

  hipLaunchKernelGGL(einsum_ts, dim3((T_ + 127) / 128, (S_ + 63) / 64, B_), dim3(256),
                     0, stream, wsp, enc, al);
  hipLaunchKernelGGL(softmax_stats, dim3((S_ + 63) / 64, B_), dim3(256), 0, stream, al, pistats);
  hipLaunchKernelGGL(norm_kernel, dim3(NMU / 4 / 256), dim3(256), 0, stream, al, msk, pistats, mu);
  hipLaunchKernelGGL(dp_skew2, dim3(B_), dim3(256), 0, stream, mu, mu, pi);
}

// Round 17
// 1073.462 us; speedup vs baseline: 2.5213x; 1.1102x over previous
//
#include <hip/hip_runtime.h>
#include <hip/hip_bf16.h>

#define B_ 32
#define T_ 2000
#define S_ 400
#define C0_ 80
#define H_ 256

static constexpr float NEGV = -1e9f;
static constexpr int NMU  = B_ * T_ * S_;       // 25,600,000
static constexpr int NPI  = 2 * NMU;            // 51,200,000

typedef _Float16 f16x8 __attribute__((ext_vector_type(8)));
typedef float    f32x4 __attribute__((ext_vector_type(4)));

// ---------------- weight repack: wcat[co][k*CPAD+ci] = w[k][ci][co] ------
__global__ __launch_bounds__(256)
void wprep(const float* __restrict__ w, _Float16* __restrict__ wcat,
           int CIN, int CPAD)
{
  const int tot = 256 * 5 * CPAD;
  int idx = blockIdx.x * 256 + threadIdx.x;
  if (idx >= tot) return;
  int co  = idx / (5 * CPAD);
  int rem = idx - co * (5 * CPAD);
  int k   = rem / CPAD;
  int ci  = rem - k * CPAD;
  float v = (ci < CIN) ? w[((size_t)k * CIN + ci) * H_ + co] : 0.f;
  wcat[idx] = (_Float16)v;
}

// ---------------- cast src_enc to f16 ------------------------------------
__global__ __launch_bounds__(256)
void ecast(const float* __restrict__ e, _Float16* __restrict__ ef)
{
  const int n4 = B_ * S_ * H_ / 4;
  int idx = blockIdx.x * 256 + threadIdx.x;
  if (idx >= n4) return;
  float4 v = ((const float4*)e)[idx];
  _Float16* d = ef + (size_t)idx * 4;
  d[0] = (_Float16)v.x; d[1] = (_Float16)v.y;
  d[2] = (_Float16)v.z; d[3] = (_Float16)v.w;
}

// ---------------- conv1d (K=5, SAME) + bias + tanh via f16 MFMA ----------
template<int CIN, int CPAD, bool INF32, bool OUTF32>
__global__ __launch_bounds__(256)
void conv_mfma(const void* __restrict__ xin, const _Float16* __restrict__ wcat,
               const float* __restrict__ bias, void* __restrict__ yout)
{
  constexpr int KK  = 5 * CPAD;      // 480 / 1280
  constexpr int NS  = KK / 32;       // 15 / 40
  constexpr int STR = CPAD + 8;      // LDS row stride
  __shared__ _Float16 xs[68 * STR];
  const int b   = blockIdx.y;
  const int t0  = blockIdx.x * 64;
  const int tid = threadIdx.x;
  const int w   = tid >> 6;
  const int l   = tid & 63;

  if constexpr (INF32) {
    const float* xb = (const float*)xin + (size_t)b * T_ * CIN;
    constexpr int NG = CPAD / 4;
    for (int idx = tid; idx < 68 * NG; idx += 256) {
      int j = idx / NG, g = idx - j * NG;
      int t = t0 - 2 + j;
      int c = g * 4;
      float4 v = make_float4(0.f, 0.f, 0.f, 0.f);
      if (t >= 0 && t < T_ && c < CIN) v = *(const float4*)&xb[(size_t)t * CIN + c];
      _Float16* d = &xs[j * STR + c];
      d[0] = (_Float16)v.x; d[1] = (_Float16)v.y;
      d[2] = (_Float16)v.z; d[3] = (_Float16)v.w;
    }
  } else {
    const _Float16* xb = (const _Float16*)xin + (size_t)b * T_ * CIN;
    constexpr int NG = CPAD / 8;
    for (int idx = tid; idx < 68 * NG; idx += 256) {
      int j = idx / NG, g = idx - j * NG;
      int t = t0 - 2 + j;
      f16x8 v = {(_Float16)0,(_Float16)0,(_Float16)0,(_Float16)0,
                 (_Float16)0,(_Float16)0,(_Float16)0,(_Float16)0};
      if (t >= 0 && t < T_) v = *(const f16x8*)&xb[(size_t)t * CIN + g * 8];
      *(f16x8*)&xs[j * STR + g * 8] = v;
    }
  }
  __syncthreads();

  const int lr = l & 15;
  const int lk = (l >> 4) * 8;

  f32x4 acc[4][4];
  const f32x4 zz = {0.f, 0.f, 0.f, 0.f};
#pragma unroll
  for (int i = 0; i < 4; i++)
#pragma unroll
    for (int j = 0; j < 4; j++) acc[i][j] = zz;

  const _Float16* wbase = wcat + (size_t)(w * 64 + lr) * KK + lk;

  for (int kk = 0; kk < NS; kk++) {
    const int p  = kk * 32;
    const int k  = p / CPAD;
    const int ci = p - k * CPAD;
    f16x8 a0 = *(const f16x8*)&xs[( 0 + lr + k) * STR + ci + lk];
    f16x8 a1 = *(const f16x8*)&xs[(16 + lr + k) * STR + ci + lk];
    f16x8 a2 = *(const f16x8*)&xs[(32 + lr + k) * STR + ci + lk];
    f16x8 a3 = *(const f16x8*)&xs[(48 + lr + k) * STR + ci + lk];
    f16x8 w0 = *(const f16x8*)&wbase[(size_t)( 0) * KK + p];
    f16x8 w1 = *(const f16x8*)&wbase[(size_t)(16) * KK + p];
    f16x8 w2 = *(const f16x8*)&wbase[(size_t)(32) * KK + p];
    f16x8 w3 = *(const f16x8*)&wbase[(size_t)(48) * KK + p];
    acc[0][0] = __builtin_amdgcn_mfma_f32_16x16x32_f16(a0, w0, acc[0][0], 0, 0, 0);
    acc[0][1] = __builtin_amdgcn_mfma_f32_16x16x32_f16(a0, w1, acc[0][1], 0, 0, 0);
    acc[0][2] = __builtin_amdgcn_mfma_f32_16x16x32_f16(a0, w2, acc[0][2], 0, 0, 0);
    acc[0][3] = __builtin_amdgcn_mfma_f32_16x16x32_f16(a0, w3, acc[0][3], 0, 0, 0);
    acc[1][0] = __builtin_amdgcn_mfma_f32_16x16x32_f16(a1, w0, acc[1][0], 0, 0, 0);
    acc[1][1] = __builtin_amdgcn_mfma_f32_16x16x32_f16(a1, w1, acc[1][1], 0, 0, 0);
    acc[1][2] = __builtin_amdgcn_mfma_f32_16x16x32_f16(a1, w2, acc[1][2], 0, 0, 0);
    acc[1][3] = __builtin_amdgcn_mfma_f32_16x16x32_f16(a1, w3, acc[1][3], 0, 0, 0);
    acc[2][0] = __builtin_amdgcn_mfma_f32_16x16x32_f16(a2, w0, acc[2][0], 0, 0, 0);
    acc[2][1] = __builtin_amdgcn_mfma_f32_16x16x32_f16(a2, w1, acc[2][1], 0, 0, 0);
    acc[2][2] = __builtin_amdgcn_mfma_f32_16x16x32_f16(a2, w2, acc[2][2], 0, 0, 0);
    acc[2][3] = __builtin_amdgcn_mfma_f32_16x16x32_f16(a2, w3, acc[2][3], 0, 0, 0);
    acc[3][0] = __builtin_amdgcn_mfma_f32_16x16x32_f16(a3, w0, acc[3][0], 0, 0, 0);
    acc[3][1] = __builtin_amdgcn_mfma_f32_16x16x32_f16(a3, w1, acc[3][1], 0, 0, 0);
    acc[3][2] = __builtin_amdgcn_mfma_f32_16x16x32_f16(a3, w2, acc[3][2], 0, 0, 0);
    acc[3][3] = __builtin_amdgcn_mfma_f32_16x16x32_f16(a3, w3, acc[3][3], 0, 0, 0);
  }

#pragma unroll
  for (int ct = 0; ct < 4; ct++) {
    const int co = w * 64 + ct * 16 + lr;
    const float bv = bias[co];
#pragma unroll
    for (int tt = 0; tt < 4; tt++) {
#pragma unroll
      for (int r = 0; r < 4; r++) {
        const int t = t0 + tt * 16 + (l >> 4) * 4 + r;
        if (t < T_) {
          float v = tanhf(acc[tt][ct][r] + bv);
          if constexpr (OUTF32)
            ((float*)yout)[((size_t)b * T_ + t) * H_ + co] = v;
          else
            ((_Float16*)yout)[((size_t)b * T_ + t) * H_ + co] = (_Float16)v;
        }
      }
    }
  }
}

// ---------------- einsum via f16 MFMA: W[b,t,s] = Wspec[b,t,:].enc[b,s,:]
// Block: 64 t-rows x 256 s-cols, 4 waves (wave w: s = s0+w*64..+63).
// A tile (Wspec fp32 -> f16) staged in LDS; B fragments = enc_f16 rows from
// L2 (reused across the 32 t-blocks of each batch). Same fragment pattern
// as conv_mfma (mfma(X,Y) = X*Y^T for [16][K] row-major fragments).
__global__ __launch_bounds__(256)
void einsum_mfma(const float* __restrict__ A, const _Float16* __restrict__ E,
                 float* __restrict__ Wg)
{
  constexpr int STR = H_ + 8;        // 264
  __shared__ _Float16 xs[64 * STR];  // 33.8 KB
  const int b   = blockIdx.z;
  const int t0  = blockIdx.x * 64;
  const int s0  = blockIdx.y * 256;
  const int tid = threadIdx.x;
  const int w   = tid >> 6;
  const int l   = tid & 63;

  // stage A tile (fp32 -> f16)
  const float* Ab = A + (size_t)b * T_ * H_;
  for (int idx = tid; idx < 64 * 64; idx += 256) {
    int row = idx >> 6, g = idx & 63;
    int t = t0 + row;
    float4 v = make_float4(0.f, 0.f, 0.f, 0.f);
    if (t < T_) v = *(const float4*)&Ab[(size_t)t * H_ + 4 * g];
    _Float16* d = &xs[row * STR + 4 * g];
    d[0] = (_Float16)v.x; d[1] = (_Float16)v.y;
    d[2] = (_Float16)v.z; d[3] = (_Float16)v.w;
  }
  __syncthreads();

  const int lr = l & 15;
  const int lk = (l >> 4) * 8;

  f32x4 acc[4][4];
  const f32x4 zz = {0.f, 0.f, 0.f, 0.f};
#pragma unroll
  for (int i = 0; i < 4; i++)
#pragma unroll
    for (int j = 0; j < 4; j++) acc[i][j] = zz;

  const _Float16* Eb = E + (size_t)b * S_ * H_;
  const int sr = s0 + w * 64 + lr;
  const _Float16* e0 = Eb + (size_t)((sr      < S_) ? sr      : (S_ - 1)) * H_ + lk;
  const _Float16* e1 = Eb + (size_t)((sr + 16 < S_) ? sr + 16 : (S_ - 1)) * H_ + lk;
  const _Float16* e2 = Eb + (size_t)((sr + 32 < S_) ? sr + 32 : (S_ - 1)) * H_ + lk;
  const _Float16* e3 = Eb + (size_t)((sr + 48 < S_) ? sr + 48 : (S_ - 1)) * H_ + lk;

#pragma unroll
  for (int kk = 0; kk < 8; kk++) {
    const int p = kk * 32;
    f16x8 a0 = *(const f16x8*)&xs[( 0 + lr) * STR + p + lk];
    f16x8 a1 = *(const f16x8*)&xs[(16 + lr) * STR + p + lk];
    f16x8 a2 = *(const f16x8*)&xs[(32 + lr) * STR + p + lk];
    f16x8 a3 = *(const f16x8*)&xs[(48 + lr) * STR + p + lk];
    f16x8 w0 = *(const f16x8*)&e0[p];
    f16x8 w1 = *(const f16x8*)&e1[p];
    f16x8 w2 = *(const f16x8*)&e2[p];
    f16x8 w3 = *(const f16x8*)&e3[p];
    acc[0][0] = __builtin_amdgcn_mfma_f32_16x16x32_f16(a0, w0, acc[0][0], 0, 0, 0);
    acc[0][1] = __builtin_amdgcn_mfma_f32_16x16x32_f16(a0, w1, acc[0][1], 0, 0, 0);
    acc[0][2] = __builtin_amdgcn_mfma_f32_16x16x32_f16(a0, w2, acc[0][2], 0, 0, 0);
    acc[0][3] = __builtin_amdgcn_mfma_f32_16x16x32_f16(a0, w3, acc[0][3], 0, 0, 0);
    acc[1][0] = __builtin_amdgcn_mfma_f32_16x16x32_f16(a1, w0, acc[1][0], 0, 0, 0);
    acc[1][1] = __builtin_amdgcn_mfma_f32_16x16x32_f16(a1, w1, acc[1][1], 0, 0, 0);
    acc[1][2] = __builtin_amdgcn_mfma_f32_16x16x32_f16(a1, w2, acc[1][2], 0, 0, 0);
    acc[1][3] = __builtin_amdgcn_mfma_f32_16x16x32_f16(a1, w3, acc[1][3], 0, 0, 0);
    acc[2][0] = __builtin_amdgcn_mfma_f32_16x16x32_f16(a2, w0, acc[2][0], 0, 0, 0);
    acc[2][1] = __builtin_amdgcn_mfma_f32_16x16x32_f16(a2, w1, acc[2][1], 0, 0, 0);
    acc[2][2] = __builtin_amdgcn_mfma_f32_16x16x32_f16(a2, w2, acc[2][2], 0, 0, 0);
    acc[2][3] = __builtin_amdgcn_mfma_f32_16x16x32_f16(a2, w3, acc[2][3], 0, 0, 0);
    acc[3][0] = __builtin_amdgcn_mfma_f32_16x16x32_f16(a3, w0, acc[3][0], 0, 0, 0);
    acc[3][1] = __builtin_amdgcn_mfma_f32_16x16x32_f16(a3, w1, acc[3][1], 0, 0, 0);
    acc[3][2] = __builtin_amdgcn_mfma_f32_16x16x32_f16(a3, w2, acc[3][2], 0, 0, 0);
    acc[3][3] = __builtin_amdgcn_mfma_f32_16x16x32_f16(a3, w3, acc[3][3], 0, 0, 0);
  }

  float* Wb = Wg + (size_t)b * T_ * S_;
#pragma unroll
  for (int ct = 0; ct < 4; ct++) {
    const int s = s0 + w * 64 + ct * 16 + lr;
    if (s < S_) {
#pragma unroll
      for (int tt = 0; tt < 4; tt++) {
#pragma unroll
        for (int r = 0; r < 4; r++) {
          const int t = t0 + tt * 16 + (l >> 4) * 4 + r;
          if (t < T_) Wb[(size_t)t * S_ + s] = acc[tt][ct][r];
        }
      }
    }
  }
}

// ---------------- per-(b,s) column softmax stats over T ------------------
__global__ __launch_bounds__(256)
void softmax_stats(const float* __restrict__ Wg, float* __restrict__ statsOut)
{
  const int b  = blockIdx.y;
  const int tx = threadIdx.x & 63;
  const int ty = threadIdx.x >> 6;            // 0..3
  const int s  = blockIdx.x * 64 + tx;
  const bool act = (s < S_);
  float m = -1e30f, l = 0.f;
  if (act) {
    const float* col = Wg + (size_t)b * T_ * S_ + s;
#pragma unroll 4
    for (int t = ty; t < T_; t += 4) {
      float v  = col[(size_t)t * S_];
      float nm = fmaxf(m, v);
      l = l * __expf(m - nm) + __expf(v - nm);
      m = nm;
    }
  }
  __shared__ float rm[4][64], rl[4][64];
  rm[ty][tx] = m; rl[ty][tx] = l;
  __syncthreads();
  if (ty == 0 && act) {
    float M = rm[0][tx];
#pragma unroll
    for (int q = 1; q < 4; q++) M = fmaxf(M, rm[q][tx]);
    float L = 0.f;
#pragma unroll
    for (int q = 0; q < 4; q++) L += rl[q][tx] * __expf(rm[q][tx] - M);
    statsOut[(size_t)b * S_ + s] = M + __logf(L);
  }
}

// ---------------- normalize: al = exp(raw-stat); wdp = al*mask*log2e ----
__global__ __launch_bounds__(256)
void norm_kernel(float* __restrict__ al, const float* __restrict__ Mk,
                 const float* __restrict__ stats, float* __restrict__ wdp)
{
  constexpr float C2 = 1.44269504f;
  const int gid = blockIdx.x * 256 + threadIdx.x;
  if (gid >= NMU / 4) return;
  const int b   = gid / (T_ * S_ / 4);
  const int rem = gid - b * (T_ * S_ / 4);
  const int s4  = rem % (S_ / 4);
  const float4 st4 = *(const float4*)&stats[(size_t)b * S_ + 4 * s4];
  float4 r = ((const float4*)al)[gid];
  float4 k = ((const float4*)Mk)[gid];
  float4 a;
  a.x = __expf(r.x - st4.x);
  a.y = __expf(r.y - st4.y);
  a.z = __expf(r.z - st4.z);
  a.w = __expf(r.w - st4.w);
  ((float4*)al)[gid] = a;
  ((float4*)wdp)[gid] = make_float4(a.x * k.x * C2, a.y * k.y * C2,
                                    a.z * k.z * C2, a.w * k.w * C2);
}

// ---------------- DP: skewed 4-wave pipeline, 8 rows/phase ---------------
__global__ __launch_bounds__(256, 1)
void dp_skew2(const float* Wdp, float* muOut, float* piOut)
{
  __shared__ float ring[64 * S_];     // 102.4 KB
  __shared__ float bnd[32][4];
  const int b = blockIdx.x;
  const int w = threadIdx.x >> 6;
  const int l = threadIdx.x & 63;
  const int lc = (l < 50) ? l : 49;
  const bool act = (l < 50);
  const int sc = 100 * w + 2 * lc;

  const float* wb  = Wdp   + (size_t)b * T_ * S_;
  float*       mub = muOut + (size_t)b * T_ * S_;
  float*       pib = piOut + (size_t)(2 * b) * T_ * S_;

  constexpr float LN2  = 0.693147181f;
  constexpr float NEGN = -1.44269504e9f;   // -1e9 * log2(e)

#define DMA(row)                                                            \
  { const char* s_ = (const char*)(wb + (size_t)(row) * S_);                \
    char* d_ = (char*)ring + (((row) & 63) * 1600);                         \
    __builtin_amdgcn_global_load_lds(                                       \
      (const __attribute__((address_space(1))) void*)(s_ + l * 16),         \
      (__attribute__((address_space(3))) void*)(d_ + l * 16), 16, 0, 0);    \
    if (l < 36)                                                             \
      __builtin_amdgcn_global_load_lds(                                     \
        (const __attribute__((address_space(1))) void*)(s_ + 1024 + l*16),  \
        (__attribute__((address_space(3))) void*)(d_ + 1024 + l*16), 16, 0, 0); }

  // prologue: rows 0..23 (6 per wave)
#pragma unroll
  for (int i = 0; i < 6; ++i) { const int r0 = 6 * w + i; DMA(r0) }
  asm volatile("s_waitcnt vmcnt(0)" ::: "memory");
  __syncthreads();

  float n0 = NEGN, n1 = NEGN;

  for (int p = 0; p <= 253; ++p) {
    __builtin_amdgcn_s_barrier();
    const int j = p - w - 1;

    {
      const int dr = 8 * p + 24 + 2 * w;
      if (dr < T_) DMA(dr)
      const int dr1 = dr + 1;
      if (dr1 < T_) DMA(dr1)
    }

    if (p == w) {
      float2 c0v = *(const float2*)&ring[sc];
      n0 = c0v.x + ((sc == 0) ? 0.f : NEGN);
      n1 = c0v.y + NEGN;
      if (act) {
        *(float2*)&mub[sc] = make_float2(n0 * LN2, n1 * LN2);
        *(float4*)&pib[2 * sc] = make_float4(1.f, 0.f, 1.f, 0.f);
      }
      if (l == 49) bnd[0][w] = n1;
    } else if (j >= 0 && j <= 249) {
      const int tb = 8 * j + 1;
      float2 cur[8];
      float  bq[8];
#pragma unroll
      for (int k = 0; k < 8; ++k) {
        const int t = tb + k;
        cur[k] = (t < T_) ? *(const float2*)&ring[(t & 63) * S_ + sc]
                          : make_float2(0.f, 0.f);
        bq[k] = (w > 0) ? bnd[(t - 1) & 31][w - 1] : NEGN;
      }
      float* mrow = mub + (size_t)tb * S_ + sc;
      float* prow = pib + (size_t)tb * (2 * S_) + 2 * sc;
#pragma unroll
      for (int k = 0; k < 8; ++k) {
        const int t = tb + k;
        if (t < T_) {
          float sh = __shfl_up(n1, 1);
          float sft0 = (l == 0) ? bq[k] : sh;
          float d0 = n0 - sft0;
          float e0; asm("v_exp_f32 %0, %1" : "=v"(e0) : "v"(-fabsf(d0)));
          float q0 = 1.f + e0;
          float lg0; asm("v_log_f32 %0, %1" : "=v"(lg0) : "v"(q0));
          float rc0; asm("v_rcp_f32 %0, %1" : "=v"(rc0) : "v"(q0));
          float p00 = (d0 >= 0.f) ? rc0 : 1.f - rc0;
          float nn0 = cur[k].x + fmaxf(n0, sft0) + lg0;
          float d1 = n1 - n0;
          float e1; asm("v_exp_f32 %0, %1" : "=v"(e1) : "v"(-fabsf(d1)));
          float q1 = 1.f + e1;
          float lg1; asm("v_log_f32 %0, %1" : "=v"(lg1) : "v"(q1));
          float rc1; asm("v_rcp_f32 %0, %1" : "=v"(rc1) : "v"(q1));
          float p01 = (d1 >= 0.f) ? rc1 : 1.f - rc1;
          float nn1 = cur[k].y + fmaxf(n1, n0) + lg1;
          if (act) {
            *(float2*)mrow = make_float2(nn0 * LN2, nn1 * LN2);
            *(float4*)prow = make_float4(p00, 1.f - p00, p01, 1.f - p01);
          }
          n0 = nn0; n1 = nn1;
          if (l == 49) bnd[t & 31][w] = n1;
        }
        mrow += S_;
        prow += 2 * S_;
      }
    }
    asm volatile("s_waitcnt lgkmcnt(0)" ::: "memory");
    asm volatile("s_waitcnt vmcnt(56)" ::: "memory");
  }
#undef DMA
}

// -------------------------------------------------------------------------
extern "C" void kernel_launch(void* const* d_in, const int* in_sizes, int n_in,
                              void* d_out, int out_size, void* d_ws, size_t ws_size,
                              hipStream_t stream)
{
  (void)in_sizes; (void)n_in; (void)out_size; (void)d_ws; (void)ws_size;
  const float* x   = (const float*)d_in[0];
  const float* enc = (const float*)d_in[1];
  const float* msk = (const float*)d_in[2];
  const float* w1  = (const float*)d_in[3];
  const float* b1  = (const float*)d_in[4];
  const float* w2  = (const float*)d_in[5];
  const float* b2  = (const float*)d_in[6];
  const float* w3  = (const float*)d_in[7];
  const float* b3  = (const float*)d_in[8];

  float* out = (float*)d_out;
  float* mu  = out;                       // [B,T,S]  (holds wdp before dp)
  float* pi  = out + NMU;                 // [B,T,S,2]
  float* al  = out + NMU + NPI;           // [B,T,S]
  float* wsp = out + NMU + NPI + NMU;     // [B,T,H] fp32

  // scratch inside pi region (consumed before dp_skew2 writes pi)
  _Float16*  h1  = (_Float16*)(pi + 26000000);       // 16.384M halves
  _Float16*  h2  = (_Float16*)(pi + 35000000);       // 16.384M halves
  _Float16*  wc1 = (_Float16*)(pi + 44000000);
  _Float16*  wc2 = (_Float16*)(pi + 44100000);
  _Float16*  wc3 = (_Float16*)(pi + 44300000);
  _Float16*  encf = (_Float16*)(pi + 44600000);      // 3.28M halves
  float*     pistats = pi + NPI - 13056;             // [B,S] softmax stats

  hipLaunchKernelGGL(wprep, dim3((256*5*96 +255)/256), dim3(256), 0, stream, w1, wc1, C0_, 96);
  hipLaunchKernelGGL(wprep, dim3((256*5*256+255)/256), dim3(256), 0, stream, w2, wc2, H_, 256);
  hipLaunchKernelGGL(wprep, dim3((256*5*256+255)/256), dim3(256), 0, stream, w3, wc3, H_, 256);
  hipLaunchKernelGGL(ecast, dim3(B_*S_*H_/4/256), dim3(256), 0, stream, enc, encf);

  dim3 cgrid((T_ + 63) / 64, B_);
  hipLaunchKernelGGL((conv_mfma<C0_,  96, true,  false>), cgrid, dim3(256), 0, stream,
                     (const void*)x,  wc1, b1, (void*)h1);
  hipLaunchKernelGGL((conv_mfma<H_,  256, false, false>), cgrid, dim3(256), 0, stream,
                     (const void*)h1, wc2, b2, (void*)h2);
  hipLaunchKernelGGL((conv_mfma<H_,  256, false, true >), cgrid, dim3(256), 0, stream,
                     (const void*)h2, wc3, b3, (void*)wsp);

  hipLaunchKernelGGL(einsum_mfma, dim3((T_ + 63) / 64, (S_ + 255) / 256, B_), dim3(256),
                     0, stream, wsp, encf, al);
  hipLaunchKernelGGL(softmax_stats, dim3((S_ + 63) / 64, B_), dim3(256), 0, stream, al, pistats);
  hipLaunchKernelGGL(norm_kernel, dim3(NMU / 4 / 256), dim3(256), 0, stream, al, msk, pistats, mu);
  hipLaunchKernelGGL(dp_skew2, dim3(B_), dim3(256), 0, stream, mu, mu, pi);
}

// Round 18
// 1039.273 us; speedup vs baseline: 2.6042x; 1.0329x over previous
//
#include <hip/hip_runtime.h>
#include <hip/hip_bf16.h>

#define B_ 32
#define T_ 2000
#define S_ 400
#define C0_ 80
#define H_ 256

static constexpr float NEGV = -1e9f;
static constexpr int NMU  = B_ * T_ * S_;       // 25,600,000
static constexpr int NPI  = 2 * NMU;            // 51,200,000

typedef _Float16 f16x8 __attribute__((ext_vector_type(8)));
typedef float    f32x4 __attribute__((ext_vector_type(4)));

// ---------------- weight repack: wcat[co][k*CPAD+ci] = w[k][ci][co] ------
__global__ __launch_bounds__(256)
void wprep(const float* __restrict__ w, _Float16* __restrict__ wcat,
           int CIN, int CPAD)
{
  const int tot = 256 * 5 * CPAD;
  int idx = blockIdx.x * 256 + threadIdx.x;
  if (idx >= tot) return;
  int co  = idx / (5 * CPAD);
  int rem = idx - co * (5 * CPAD);
  int k   = rem / CPAD;
  int ci  = rem - k * CPAD;
  float v = (ci < CIN) ? w[((size_t)k * CIN + ci) * H_ + co] : 0.f;
  wcat[idx] = (_Float16)v;
}

// ---------------- cast src_enc to f16 ------------------------------------
__global__ __launch_bounds__(256)
void ecast(const float* __restrict__ e, _Float16* __restrict__ ef)
{
  const int n4 = B_ * S_ * H_ / 4;
  int idx = blockIdx.x * 256 + threadIdx.x;
  if (idx >= n4) return;
  float4 v = ((const float4*)e)[idx];
  _Float16* d = ef + (size_t)idx * 4;
  d[0] = (_Float16)v.x; d[1] = (_Float16)v.y;
  d[2] = (_Float16)v.z; d[3] = (_Float16)v.w;
}

// ---------------- conv1d (K=5, SAME) + bias + tanh via f16 MFMA ----------
template<int CIN, int CPAD, bool INF32, bool OUTF32>
__global__ __launch_bounds__(256)
void conv_mfma(const void* __restrict__ xin, const _Float16* __restrict__ wcat,
               const float* __restrict__ bias, void* __restrict__ yout)
{
  constexpr int KK  = 5 * CPAD;      // 480 / 1280
  constexpr int NS  = KK / 32;       // 15 / 40
  constexpr int STR = CPAD + 8;      // LDS row stride
  __shared__ _Float16 xs[68 * STR];
  const int b   = blockIdx.y;
  const int t0  = blockIdx.x * 64;
  const int tid = threadIdx.x;
  const int w   = tid >> 6;
  const int l   = tid & 63;

  if constexpr (INF32) {
    const float* xb = (const float*)xin + (size_t)b * T_ * CIN;
    constexpr int NG = CPAD / 4;
    for (int idx = tid; idx < 68 * NG; idx += 256) {
      int j = idx / NG, g = idx - j * NG;
      int t = t0 - 2 + j;
      int c = g * 4;
      float4 v = make_float4(0.f, 0.f, 0.f, 0.f);
      if (t >= 0 && t < T_ && c < CIN) v = *(const float4*)&xb[(size_t)t * CIN + c];
      _Float16* d = &xs[j * STR + c];
      d[0] = (_Float16)v.x; d[1] = (_Float16)v.y;
      d[2] = (_Float16)v.z; d[3] = (_Float16)v.w;
    }
  } else {
    const _Float16* xb = (const _Float16*)xin + (size_t)b * T_ * CIN;
    constexpr int NG = CPAD / 8;
    for (int idx = tid; idx < 68 * NG; idx += 256) {
      int j = idx / NG, g = idx - j * NG;
      int t = t0 - 2 + j;
      f16x8 v = {(_Float16)0,(_Float16)0,(_Float16)0,(_Float16)0,
                 (_Float16)0,(_Float16)0,(_Float16)0,(_Float16)0};
      if (t >= 0 && t < T_) v = *(const f16x8*)&xb[(size_t)t * CIN + g * 8];
      *(f16x8*)&xs[j * STR + g * 8] = v;
    }
  }
  __syncthreads();

  const int lr = l & 15;
  const int lk = (l >> 4) * 8;

  f32x4 acc[4][4];
  const f32x4 zz = {0.f, 0.f, 0.f, 0.f};
#pragma unroll
  for (int i = 0; i < 4; i++)
#pragma unroll
    for (int j = 0; j < 4; j++) acc[i][j] = zz;

  const _Float16* wbase = wcat + (size_t)(w * 64 + lr) * KK + lk;

  for (int kk = 0; kk < NS; kk++) {
    const int p  = kk * 32;
    const int k  = p / CPAD;
    const int ci = p - k * CPAD;
    f16x8 a0 = *(const f16x8*)&xs[( 0 + lr + k) * STR + ci + lk];
    f16x8 a1 = *(const f16x8*)&xs[(16 + lr + k) * STR + ci + lk];
    f16x8 a2 = *(const f16x8*)&xs[(32 + lr + k) * STR + ci + lk];
    f16x8 a3 = *(const f16x8*)&xs[(48 + lr + k) * STR + ci + lk];
    f16x8 w0 = *(const f16x8*)&wbase[(size_t)( 0) * KK + p];
    f16x8 w1 = *(const f16x8*)&wbase[(size_t)(16) * KK + p];
    f16x8 w2 = *(const f16x8*)&wbase[(size_t)(32) * KK + p];
    f16x8 w3 = *(const f16x8*)&wbase[(size_t)(48) * KK + p];
    acc[0][0] = __builtin_amdgcn_mfma_f32_16x16x32_f16(a0, w0, acc[0][0], 0, 0, 0);
    acc[0][1] = __builtin_amdgcn_mfma_f32_16x16x32_f16(a0, w1, acc[0][1], 0, 0, 0);
    acc[0][2] = __builtin_amdgcn_mfma_f32_16x16x32_f16(a0, w2, acc[0][2], 0, 0, 0);
    acc[0][3] = __builtin_amdgcn_mfma_f32_16x16x32_f16(a0, w3, acc[0][3], 0, 0, 0);
    acc[1][0] = __builtin_amdgcn_mfma_f32_16x16x32_f16(a1, w0, acc[1][0], 0, 0, 0);
    acc[1][1] = __builtin_amdgcn_mfma_f32_16x16x32_f16(a1, w1, acc[1][1], 0, 0, 0);
    acc[1][2] = __builtin_amdgcn_mfma_f32_16x16x32_f16(a1, w2, acc[1][2], 0, 0, 0);
    acc[1][3] = __builtin_amdgcn_mfma_f32_16x16x32_f16(a1, w3, acc[1][3], 0, 0, 0);
    acc[2][0] = __builtin_amdgcn_mfma_f32_16x16x32_f16(a2, w0, acc[2][0], 0, 0, 0);
    acc[2][1] = __builtin_amdgcn_mfma_f32_16x16x32_f16(a2, w1, acc[2][1], 0, 0, 0);
    acc[2][2] = __builtin_amdgcn_mfma_f32_16x16x32_f16(a2, w2, acc[2][2], 0, 0, 0);
    acc[2][3] = __builtin_amdgcn_mfma_f32_16x16x32_f16(a2, w3, acc[2][3], 0, 0, 0);
    acc[3][0] = __builtin_amdgcn_mfma_f32_16x16x32_f16(a3, w0, acc[3][0], 0, 0, 0);
    acc[3][1] = __builtin_amdgcn_mfma_f32_16x16x32_f16(a3, w1, acc[3][1], 0, 0, 0);
    acc[3][2] = __builtin_amdgcn_mfma_f32_16x16x32_f16(a3, w2, acc[3][2], 0, 0, 0);
    acc[3][3] = __builtin_amdgcn_mfma_f32_16x16x32_f16(a3, w3, acc[3][3], 0, 0, 0);
  }

#pragma unroll
  for (int ct = 0; ct < 4; ct++) {
    const int co = w * 64 + ct * 16 + lr;
    const float bv = bias[co];
#pragma unroll
    for (int tt = 0; tt < 4; tt++) {
#pragma unroll
      for (int r = 0; r < 4; r++) {
        const int t = t0 + tt * 16 + (l >> 4) * 4 + r;
        if (t < T_) {
          float v = tanhf(acc[tt][ct][r] + bv);
          if constexpr (OUTF32)
            ((float*)yout)[((size_t)b * T_ + t) * H_ + co] = v;
          else
            ((_Float16*)yout)[((size_t)b * T_ + t) * H_ + co] = (_Float16)v;
        }
      }
    }
  }
}

// ---------------- einsum via f16 MFMA + fused column-stats partials ------
// W[b,t,s] = Wspec[b,t,:].enc[b,s,:]; additionally each block reduces its
// 64 t-rows per column s to (M, L) partials: per-lane 16-value max/sumexp
// then shfl_xor(16/32) tree across the 4 lanes sharing a column.
__global__ __launch_bounds__(256)
void einsum_mfma(const float* __restrict__ A, const _Float16* __restrict__ E,
                 float* __restrict__ Wg,
                 float* __restrict__ pm, float* __restrict__ pl)
{
  constexpr int STR = H_ + 8;        // 264
  __shared__ _Float16 xs[64 * STR];  // 33.8 KB
  const int b   = blockIdx.z;
  const int t0  = blockIdx.x * 64;
  const int s0  = blockIdx.y * 256;
  const int tid = threadIdx.x;
  const int w   = tid >> 6;
  const int l   = tid & 63;

  // stage A tile (fp32 -> f16)
  const float* Ab = A + (size_t)b * T_ * H_;
  for (int idx = tid; idx < 64 * 64; idx += 256) {
    int row = idx >> 6, g = idx & 63;
    int t = t0 + row;
    float4 v = make_float4(0.f, 0.f, 0.f, 0.f);
    if (t < T_) v = *(const float4*)&Ab[(size_t)t * H_ + 4 * g];
    _Float16* d = &xs[row * STR + 4 * g];
    d[0] = (_Float16)v.x; d[1] = (_Float16)v.y;
    d[2] = (_Float16)v.z; d[3] = (_Float16)v.w;
  }
  __syncthreads();

  const int lr = l & 15;
  const int lk = (l >> 4) * 8;

  f32x4 acc[4][4];
  const f32x4 zz = {0.f, 0.f, 0.f, 0.f};
#pragma unroll
  for (int i = 0; i < 4; i++)
#pragma unroll
    for (int j = 0; j < 4; j++) acc[i][j] = zz;

  const _Float16* Eb = E + (size_t)b * S_ * H_;
  const int sr = s0 + w * 64 + lr;
  const _Float16* e0 = Eb + (size_t)((sr      < S_) ? sr      : (S_ - 1)) * H_ + lk;
  const _Float16* e1 = Eb + (size_t)((sr + 16 < S_) ? sr + 16 : (S_ - 1)) * H_ + lk;
  const _Float16* e2 = Eb + (size_t)((sr + 32 < S_) ? sr + 32 : (S_ - 1)) * H_ + lk;
  const _Float16* e3 = Eb + (size_t)((sr + 48 < S_) ? sr + 48 : (S_ - 1)) * H_ + lk;

#pragma unroll
  for (int kk = 0; kk < 8; kk++) {
    const int p = kk * 32;
    f16x8 a0 = *(const f16x8*)&xs[( 0 + lr) * STR + p + lk];
    f16x8 a1 = *(const f16x8*)&xs[(16 + lr) * STR + p + lk];
    f16x8 a2 = *(const f16x8*)&xs[(32 + lr) * STR + p + lk];
    f16x8 a3 = *(const f16x8*)&xs[(48 + lr) * STR + p + lk];
    f16x8 w0 = *(const f16x8*)&e0[p];
    f16x8 w1 = *(const f16x8*)&e1[p];
    f16x8 w2 = *(const f16x8*)&e2[p];
    f16x8 w3 = *(const f16x8*)&e3[p];
    acc[0][0] = __builtin_amdgcn_mfma_f32_16x16x32_f16(a0, w0, acc[0][0], 0, 0, 0);
    acc[0][1] = __builtin_amdgcn_mfma_f32_16x16x32_f16(a0, w1, acc[0][1], 0, 0, 0);
    acc[0][2] = __builtin_amdgcn_mfma_f32_16x16x32_f16(a0, w2, acc[0][2], 0, 0, 0);
    acc[0][3] = __builtin_amdgcn_mfma_f32_16x16x32_f16(a0, w3, acc[0][3], 0, 0, 0);
    acc[1][0] = __builtin_amdgcn_mfma_f32_16x16x32_f16(a1, w0, acc[1][0], 0, 0, 0);
    acc[1][1] = __builtin_amdgcn_mfma_f32_16x16x32_f16(a1, w1, acc[1][1], 0, 0, 0);
    acc[1][2] = __builtin_amdgcn_mfma_f32_16x16x32_f16(a1, w2, acc[1][2], 0, 0, 0);
    acc[1][3] = __builtin_amdgcn_mfma_f32_16x16x32_f16(a1, w3, acc[1][3], 0, 0, 0);
    acc[2][0] = __builtin_amdgcn_mfma_f32_16x16x32_f16(a2, w0, acc[2][0], 0, 0, 0);
    acc[2][1] = __builtin_amdgcn_mfma_f32_16x16x32_f16(a2, w1, acc[2][1], 0, 0, 0);
    acc[2][2] = __builtin_amdgcn_mfma_f32_16x16x32_f16(a2, w2, acc[2][2], 0, 0, 0);
    acc[2][3] = __builtin_amdgcn_mfma_f32_16x16x32_f16(a2, w3, acc[2][3], 0, 0, 0);
    acc[3][0] = __builtin_amdgcn_mfma_f32_16x16x32_f16(a3, w0, acc[3][0], 0, 0, 0);
    acc[3][1] = __builtin_amdgcn_mfma_f32_16x16x32_f16(a3, w1, acc[3][1], 0, 0, 0);
    acc[3][2] = __builtin_amdgcn_mfma_f32_16x16x32_f16(a3, w2, acc[3][2], 0, 0, 0);
    acc[3][3] = __builtin_amdgcn_mfma_f32_16x16x32_f16(a3, w3, acc[3][3], 0, 0, 0);
  }

  float* Wb = Wg + (size_t)b * T_ * S_;
#pragma unroll
  for (int ct = 0; ct < 4; ct++) {
    const int s = s0 + w * 64 + ct * 16 + lr;
    if (s < S_) {
#pragma unroll
      for (int tt = 0; tt < 4; tt++) {
#pragma unroll
        for (int r = 0; r < 4; r++) {
          const int t = t0 + tt * 16 + (l >> 4) * 4 + r;
          if (t < T_) Wb[(size_t)t * S_ + s] = acc[tt][ct][r];
        }
      }
    }
  }

  // ---- fused per-(t-block, s) column stats ----
  const int tblk = blockIdx.x;
#pragma unroll
  for (int ct = 0; ct < 4; ct++) {
    float M = -3e38f;
#pragma unroll
    for (int tt = 0; tt < 4; tt++)
#pragma unroll
      for (int r = 0; r < 4; r++) {
        const int t = t0 + tt * 16 + (l >> 4) * 4 + r;
        if (t < T_) M = fmaxf(M, acc[tt][ct][r]);
      }
    float L = 0.f;
#pragma unroll
    for (int tt = 0; tt < 4; tt++)
#pragma unroll
      for (int r = 0; r < 4; r++) {
        const int t = t0 + tt * 16 + (l >> 4) * 4 + r;
        if (t < T_) L += __expf(acc[tt][ct][r] - M);
      }
#pragma unroll
    for (int mk = 16; mk <= 32; mk <<= 1) {
      float Mo = __shfl_xor(M, mk);
      float Lo = __shfl_xor(L, mk);
      float Mn = fmaxf(M, Mo);
      L = L * __expf(M - Mn) + Lo * __expf(Mo - Mn);
      M = Mn;
    }
    if ((l >> 4) == 0) {
      const int s = s0 + w * 64 + ct * 16 + lr;
      if (s < S_) {
        pm[((size_t)b * 32 + tblk) * S_ + s] = M;
        pl[((size_t)b * 32 + tblk) * S_ + s] = L;
      }
    }
  }
}

// ---------------- reduce 32 t-block partials -> stats[b][s] = M + lnL ----
__global__ __launch_bounds__(256)
void stats_reduce(const float* __restrict__ pm, const float* __restrict__ pl,
                  float* __restrict__ statsOut)
{
  int idx = blockIdx.x * 256 + threadIdx.x;
  if (idx >= B_ * S_) return;
  int b = idx / S_, s = idx - b * S_;
  float M = -3e38f, L = 0.f;
#pragma unroll 4
  for (int k = 0; k < 32; k++) {
    float m = pm[((size_t)b * 32 + k) * S_ + s];
    float l = pl[((size_t)b * 32 + k) * S_ + s];
    float Mn = fmaxf(M, m);
    L = L * __expf(M - Mn) + l * __expf(m - Mn);
    M = Mn;
  }
  statsOut[(size_t)b * S_ + s] = M + __logf(L);
}

// ---------------- normalize: al = exp(raw-stat); wdp = al*mask*log2e ----
__global__ __launch_bounds__(256)
void norm_kernel(float* __restrict__ al, const float* __restrict__ Mk,
                 const float* __restrict__ stats, float* __restrict__ wdp)
{
  constexpr float C2 = 1.44269504f;
  const int gid = blockIdx.x * 256 + threadIdx.x;
  if (gid >= NMU / 4) return;
  const int b   = gid / (T_ * S_ / 4);
  const int rem = gid - b * (T_ * S_ / 4);
  const int s4  = rem % (S_ / 4);
  const float4 st4 = *(const float4*)&stats[(size_t)b * S_ + 4 * s4];
  float4 r = ((const float4*)al)[gid];
  float4 k = ((const float4*)Mk)[gid];
  float4 a;
  a.x = __expf(r.x - st4.x);
  a.y = __expf(r.y - st4.y);
  a.z = __expf(r.z - st4.z);
  a.w = __expf(r.w - st4.w);
  ((float4*)al)[gid] = a;
  ((float4*)wdp)[gid] = make_float4(a.x * k.x * C2, a.y * k.y * C2,
                                    a.z * k.z * C2, a.w * k.w * C2);
}

// ---------------- DP: skewed 4-wave pipeline, 8 rows/phase ---------------
__global__ __launch_bounds__(256, 1)
void dp_skew2(const float* Wdp, float* muOut, float* piOut)
{
  __shared__ float ring[64 * S_];     // 102.4 KB
  __shared__ float bnd[32][4];
  const int b = blockIdx.x;
  const int w = threadIdx.x >> 6;
  const int l = threadIdx.x & 63;
  const int lc = (l < 50) ? l : 49;
  const bool act = (l < 50);
  const int sc = 100 * w + 2 * lc;

  const float* wb  = Wdp   + (size_t)b * T_ * S_;
  float*       mub = muOut + (size_t)b * T_ * S_;
  float*       pib = piOut + (size_t)(2 * b) * T_ * S_;

  constexpr float LN2  = 0.693147181f;
  constexpr float NEGN = -1.44269504e9f;   // -1e9 * log2(e)

#define DMA(row)                                                            \
  { const char* s_ = (const char*)(wb + (size_t)(row) * S_);                \
    char* d_ = (char*)ring + (((row) & 63) * 1600);                         \
    __builtin_amdgcn_global_load_lds(                                       \
      (const __attribute__((address_space(1))) void*)(s_ + l * 16),         \
      (__attribute__((address_space(3))) void*)(d_ + l * 16), 16, 0, 0);    \
    if (l < 36)                                                             \
      __builtin_amdgcn_global_load_lds(                                     \
        (const __attribute__((address_space(1))) void*)(s_ + 1024 + l*16),  \
        (__attribute__((address_space(3))) void*)(d_ + 1024 + l*16), 16, 0, 0); }

  // prologue: rows 0..23 (6 per wave)
#pragma unroll
  for (int i = 0; i < 6; ++i) { const int r0 = 6 * w + i; DMA(r0) }
  asm volatile("s_waitcnt vmcnt(0)" ::: "memory");
  __syncthreads();

  float n0 = NEGN, n1 = NEGN;

  for (int p = 0; p <= 253; ++p) {
    __builtin_amdgcn_s_barrier();
    const int j = p - w - 1;

    {
      const int dr = 8 * p + 24 + 2 * w;
      if (dr < T_) DMA(dr)
      const int dr1 = dr + 1;
      if (dr1 < T_) DMA(dr1)
    }

    if (p == w) {
      float2 c0v = *(const float2*)&ring[sc];
      n0 = c0v.x + ((sc == 0) ? 0.f : NEGN);
      n1 = c0v.y + NEGN;
      if (act) {
        *(float2*)&mub[sc] = make_float2(n0 * LN2, n1 * LN2);
        *(float4*)&pib[2 * sc] = make_float4(1.f, 0.f, 1.f, 0.f);
      }
      if (l == 49) bnd[0][w] = n1;
    } else if (j >= 0 && j <= 249) {
      const int tb = 8 * j + 1;
      float2 cur[8];
      float  bq[8];
#pragma unroll
      for (int k = 0; k < 8; ++k) {
        const int t = tb + k;
        cur[k] = (t < T_) ? *(const float2*)&ring[(t & 63) * S_ + sc]
                          : make_float2(0.f, 0.f);
        bq[k] = (w > 0) ? bnd[(t - 1) & 31][w - 1] : NEGN;
      }
      float* mrow = mub + (size_t)tb * S_ + sc;
      float* prow = pib + (size_t)tb * (2 * S_) + 2 * sc;
#pragma unroll
      for (int k = 0; k < 8; ++k) {
        const int t = tb + k;
        if (t < T_) {
          float sh = __shfl_up(n1, 1);
          float sft0 = (l == 0) ? bq[k] : sh;
          float d0 = n0 - sft0;
          float e0; asm("v_exp_f32 %0, %1" : "=v"(e0) : "v"(-fabsf(d0)));
          float q0 = 1.f + e0;
          float lg0; asm("v_log_f32 %0, %1" : "=v"(lg0) : "v"(q0));
          float rc0; asm("v_rcp_f32 %0, %1" : "=v"(rc0) : "v"(q0));
          float p00 = (d0 >= 0.f) ? rc0 : 1.f - rc0;
          float nn0 = cur[k].x + fmaxf(n0, sft0) + lg0;
          float d1 = n1 - n0;
          float e1; asm("v_exp_f32 %0, %1" : "=v"(e1) : "v"(-fabsf(d1)));
          float q1 = 1.f + e1;
          float lg1; asm("v_log_f32 %0, %1" : "=v"(lg1) : "v"(q1));
          float rc1; asm("v_rcp_f32 %0, %1" : "=v"(rc1) : "v"(q1));
          float p01 = (d1 >= 0.f) ? rc1 : 1.f - rc1;
          float nn1 = cur[k].y + fmaxf(n1, n0) + lg1;
          if (act) {
            *(float2*)mrow = make_float2(nn0 * LN2, nn1 * LN2);
            *(float4*)prow = make_float4(p00, 1.f - p00, p01, 1.f - p01);
          }
          n0 = nn0; n1 = nn1;
          if (l == 49) bnd[t & 31][w] = n1;
        }
        mrow += S_;
        prow += 2 * S_;
      }
    }
    asm volatile("s_waitcnt lgkmcnt(0)" ::: "memory");
    asm volatile("s_waitcnt vmcnt(56)" ::: "memory");
  }
#undef DMA
}

// -------------------------------------------------------------------------
extern "C" void kernel_launch(void* const* d_in, const int* in_sizes, int n_in,
                              void* d_out, int out_size, void* d_ws, size_t ws_size,
                              hipStream_t stream)
{
  (void)in_sizes; (void)n_in; (void)out_size; (void)d_ws; (void)ws_size;
  const float* x   = (const float*)d_in[0];
  const float* enc = (const float*)d_in[1];
  const float* msk = (const float*)d_in[2];
  const float* w1  = (const float*)d_in[3];
  const float* b1  = (const float*)d_in[4];
  const float* w2  = (const float*)d_in[5];
  const float* b2  = (const float*)d_in[6];
  const float* w3  = (const float*)d_in[7];
  const float* b3  = (const float*)d_in[8];

  float* out = (float*)d_out;
  float* mu  = out;                       // [B,T,S]  (holds wdp before dp)
  float* pi  = out + NMU;                 // [B,T,S,2]
  float* al  = out + NMU + NPI;           // [B,T,S]
  float* wsp = out + NMU + NPI + NMU;     // [B,T,H] fp32

  // scratch inside pi region (consumed before dp_skew2 writes pi)
  _Float16*  h1  = (_Float16*)(pi + 26000000);       // 16.384M halves
  _Float16*  h2  = (_Float16*)(pi + 35000000);       // 16.384M halves
  _Float16*  wc1 = (_Float16*)(pi + 44000000);
  _Float16*  wc2 = (_Float16*)(pi + 44100000);
  _Float16*  wc3 = (_Float16*)(pi + 44300000);
  _Float16*  encf = (_Float16*)(pi + 44600000);      // 3.28M halves
  float*     pm   = pi + 46300000;                   // [B][32][S] partial M
  float*     pl   = pi + 47200000;                   // [B][32][S] partial L
  float*     pistats = pi + NPI - 13056;             // [B,S] softmax stats

  hipLaunchKernelGGL(wprep, dim3((256*5*96 +255)/256), dim3(256), 0, stream, w1, wc1, C0_, 96);
  hipLaunchKernelGGL(wprep, dim3((256*5*256+255)/256), dim3(256), 0, stream, w2, wc2, H_, 256);
  hipLaunchKernelGGL(wprep, dim3((256*5*256+255)/256), dim3(256), 0, stream, w3, wc3, H_, 256);
  hipLaunchKernelGGL(ecast, dim3(B_*S_*H_/4/256), dim3(256), 0, stream, enc, encf);

  dim3 cgrid((T_ + 63) / 64, B_);
  hipLaunchKernelGGL((conv_mfma<C0_,  96, true,  false>), cgrid, dim3(256), 0, stream,
                     (const void*)x,  wc1, b1, (void*)h1);
  hipLaunchKernelGGL((conv_mfma<H_,  256, false, false>), cgrid, dim3(256), 0, stream,
                     (const void*)h1, wc2, b2, (void*)h2);
  hipLaunchKernelGGL((conv_mfma<H_,  256, false, true >), cgrid, dim3(256), 0, stream,
                     (const void*)h2, wc3, b3, (void*)wsp);

  hipLaunchKernelGGL(einsum_mfma, dim3((T_ + 63) / 64, (S_ + 255) / 256, B_), dim3(256),
                     0, stream, wsp, encf, al, pm, pl);
  hipLaunchKernelGGL(stats_reduce, dim3((B_ * S_ + 255) / 256), dim3(256), 0, stream,
                     pm, pl, pistats);
  hipLaunchKernelGGL(norm_kernel, dim3(NMU / 4 / 256), dim3(256), 0, stream, al, msk, pistats, mu);
  hipLaunchKernelGGL(dp_skew2, dim3(B_), dim3(256), 0, stream, mu, mu, pi);
}